// Round 4
// baseline (1066.573 us; speedup 1.0000x reference)
//
#include <hip/hip_runtime.h>
#include <hip/hip_bf16.h>

// Problem constants
#define Wd    96
#define Hd    96
#define HW    9216           // 96*96
#define Bn    4
#define Cn    64             // channels per section
#define C3    192            // 3*Cn
#define On    64             // out channels
#define KK    9              // 3x3 taps
#define NPIX  (Bn*HW)        // 36864
#define NFEAT (Bn*Cn*HW)     // 2359296 elements per output tensor
#define NOFF  (Bn*18*HW)     // 663552 offset elements

// ---------------------------------------------------------------------------
// diff = (ref - dist)^2 -> f32 into d_out second half (output 1).
// Deform kernel re-reads it from there.
// ---------------------------------------------------------------------------
__global__ void diff_kernel(const float* __restrict__ ref,
                            const float* __restrict__ dist,
                            float* __restrict__ out_diff) {
    int i = blockIdx.x * blockDim.x + threadIdx.x;
    if (i < NFEAT) {
        float d = ref[i] - dist[i];
        out_diff[i] = d * d;
    }
}

// ---------------------------------------------------------------------------
// offset = conv3x3(ref, offset_w) + offset_b  -> f32 in workspace
// One thread per output element [b, v, y, x]; lane dim = x (coalesced).
// ---------------------------------------------------------------------------
__global__ void offset_kernel(const float* __restrict__ ref,
                              const float* __restrict__ ow,
                              const float* __restrict__ ob,
                              float* __restrict__ off) {
    int t = blockIdx.x * blockDim.x + threadIdx.x;
    if (t >= NOFF) return;
    int x = t % Wd;
    int y = (t / Wd) % Hd;
    int v = (t / HW) % 18;
    int b = t / (HW * 18);
    float acc = ob[v];
    const float* rb = ref + (size_t)b * (Cn * HW);
    const float* wb = ow + (size_t)v * (Cn * 9);
    for (int k = 0; k < 9; ++k) {
        int ky = k / 3, kx = k % 3;
        int yy = y - 1 + ky, xx = x - 1 + kx;
        if ((unsigned)yy < (unsigned)Hd && (unsigned)xx < (unsigned)Wd) {
            const float* rp = rb + yy * Wd + xx;
            const float* wp = wb + k;
#pragma unroll
            for (int c = 0; c < Cn; ++c)
                acc += rp[c * HW] * wp[c * 9];
        }
    }
    off[t] = acc;
}

// ---------------------------------------------------------------------------
// Transpose deform_w [O,192,3,3] -> wT[(k*192+c)*64 + o] f32 (coalesced
// phase-2 reads).
// ---------------------------------------------------------------------------
__global__ void wt_kernel(const float* __restrict__ w, float* __restrict__ wt) {
    int t = blockIdx.x * blockDim.x + threadIdx.x;
    if (t >= C3 * KK * On) return;
    int o = t & 63;
    int kc = t >> 6;
    int c = kc % C3;
    int k = kc / C3;
    wt[t] = w[((size_t)o * C3 + c) * 9 + k];
}

// ---------------------------------------------------------------------------
// Deform conv. Block = 256 threads = 4 waves; block handles 8 consecutive
// pixels. Wave w fills sampled rows for pixels w and w+4 (phase 1), then
// each lane accumulates 2 outputs (o = lane) over the 1728-deep dot.
// LDS: 8 * 1728 * 4B = 55296 B.
// ---------------------------------------------------------------------------
__device__ __forceinline__ float bilin_f32(const float* pl,
                                           int y0, int x0, int y1, int x1,
                                           bool vy0, bool vx0, bool vy1, bool vx1,
                                           float w00, float w01, float w10, float w11) {
    float v00 = (vy0 && vx0) ? pl[y0 * Wd + x0] : 0.f;
    float v01 = (vy0 && vx1) ? pl[y0 * Wd + x1] : 0.f;
    float v10 = (vy1 && vx0) ? pl[y1 * Wd + x0] : 0.f;
    float v11 = (vy1 && vx1) ? pl[y1 * Wd + x1] : 0.f;
    return w00 * v00 + w01 * v01 + w10 * v10 + w11 * v11;
}

__global__ __launch_bounds__(256) void deform_kernel(
        const float* __restrict__ ref,
        const float* __restrict__ dist,
        const float* __restrict__ diff,    // d_out + NFEAT (f32)
        const float* __restrict__ off,     // ws
        const float* __restrict__ wt,      // ws
        const float* __restrict__ db,
        float* __restrict__ out) {
    __shared__ float s[8][C3 * KK];        // 8 x 1728 f32

    int tid = threadIdx.x;
    int lane = tid & 63;
    int wv = tid >> 6;                     // wave id 0..3
    int blk = blockIdx.x;

    // ---- phase 1: bilinear sampling into LDS ----
    for (int pp = 0; pp < 2; ++pp) {
        int pix = wv + pp * 4;             // LDS row
        int p = blk * 8 + pix;             // global pixel id
        int x = p % Wd;
        int y = (p / Wd) % Hd;
        int b = p / HW;
        const float* offp = off + (size_t)b * (18 * HW) + y * Wd + x;
        const float* plr = ref  + ((size_t)b * Cn + lane) * HW;
        const float* pld = dist + ((size_t)b * Cn + lane) * HW;
        const float* plq = diff + ((size_t)b * Cn + lane) * HW;
        for (int k = 0; k < 9; ++k) {
            int ky = k / 3, kx = k % 3;
            float dy = offp[(2 * k) * HW];
            float dx = offp[(2 * k + 1) * HW];
            float py = (float)(y - 1 + ky) + dy;
            float px = (float)(x - 1 + kx) + dx;
            float fy = floorf(py), fx = floorf(px);
            int y0 = (int)fy, x0 = (int)fx;
            int y1 = y0 + 1, x1 = x0 + 1;
            float ay = py - fy, ax = px - fx;
            float w00 = (1.f - ay) * (1.f - ax);
            float w01 = (1.f - ay) * ax;
            float w10 = ay * (1.f - ax);
            float w11 = ay * ax;
            bool vy0 = (unsigned)y0 < (unsigned)Hd;
            bool vy1 = (unsigned)y1 < (unsigned)Hd;
            bool vx0 = (unsigned)x0 < (unsigned)Wd;
            bool vx1 = (unsigned)x1 < (unsigned)Wd;
            s[pix][k * C3 + lane] =
                bilin_f32(plr, y0, x0, y1, x1, vy0, vx0, vy1, vx1, w00, w01, w10, w11);
            s[pix][k * C3 + Cn + lane] =
                bilin_f32(pld, y0, x0, y1, x1, vy0, vx0, vy1, vx1, w00, w01, w10, w11);
            s[pix][k * C3 + 2 * Cn + lane] =
                bilin_f32(plq, y0, x0, y1, x1, vy0, vx0, vy1, vx1, w00, w01, w10, w11);
        }
    }
    __syncthreads();

    // ---- phase 2: 1728-deep dot, 2 pixels per lane ----
    int o = lane;
    float accA = db[o];
    float accB = accA;
    const float* sA = s[wv];
    const float* sB = s[wv + 4];
#pragma unroll 8
    for (int i = 0; i < C3 * KK; ++i) {
        float wf = wt[i * 64 + o];
        accA += sA[i] * wf;
        accB += sB[i] * wf;
    }
    accA = fmaxf(accA, 0.f);
    accB = fmaxf(accB, 0.f);

    int pA = blk * 8 + wv;
    int pB = pA + 4;
    {
        int x = pA % Wd, y = (pA / Wd) % Hd, b = pA / HW;
        out[((size_t)b * On + o) * HW + y * Wd + x] = accA;
    }
    {
        int x = pB % Wd, y = (pB / Wd) % Hd, b = pB / HW;
        out[((size_t)b * On + o) * HW + y * Wd + x] = accB;
    }
}

// ---------------------------------------------------------------------------
extern "C" void kernel_launch(void* const* d_in, const int* in_sizes, int n_in,
                              void* d_out, int out_size, void* d_ws, size_t ws_size,
                              hipStream_t stream) {
    const float* ref  = (const float*)d_in[0];
    const float* dist = (const float*)d_in[1];
    const float* ow   = (const float*)d_in[2];
    const float* ob   = (const float*)d_in[3];
    const float* dw   = (const float*)d_in[4];
    const float* db   = (const float*)d_in[5];

    float* out = (float*)d_out;               // [feat | diff], each NFEAT f32

    float* ws_off = (float*)d_ws;             // NOFF f32 = 2 654 208 B
    float* ws_wt  = ws_off + NOFF;            // 110 592 f32 = 442 368 B

    diff_kernel<<<(NFEAT + 255) / 256, 256, 0, stream>>>(ref, dist, out + NFEAT);
    offset_kernel<<<(NOFF + 255) / 256, 256, 0, stream>>>(ref, ow, ob, ws_off);
    wt_kernel<<<(C3 * KK * On + 255) / 256, 256, 0, stream>>>(dw, ws_wt);
    deform_kernel<<<NPIX / 8, 256, 0, stream>>>(ref, dist, out + NFEAT,
                                                ws_off, ws_wt, db, out);
}

// Round 5
// 669.287 us; speedup vs baseline: 1.5936x; 1.5936x over previous
//
#include <hip/hip_runtime.h>
#include <hip/hip_bf16.h>

// Problem constants
#define Wd    96
#define Hd    96
#define HW    9216           // 96*96
#define Bn    4
#define Cn    64             // channels per section
#define C3    192            // 3*Cn
#define On    64             // out channels
#define KK    9              // 3x3 taps
#define NPIX  (Bn*HW)        // 36864
#define NFEAT (Bn*Cn*HW)     // 2359296 elements per output tensor
#define NOFF  (Bn*18*HW)     // 663552 offset elements

// ===========================================================================
// repack: NCHW ref/dist -> NHWC packed[b][p][c] (c = ref|dist|diff, 192),
// fused diff computation; also writes diff (NCHW f32) to d_out second half.
// Block = 256 threads handles 64 pixels x 192 channels via LDS transpose.
// ===========================================================================
#define RP_PITCH 65           // 64 + 1 pad-ish (odd stride -> conflict-free)
__global__ __launch_bounds__(256) void repack_kernel(
        const float* __restrict__ ref,
        const float* __restrict__ dist,
        float* __restrict__ packed,
        float* __restrict__ out_diff) {
    __shared__ float lds[C3][RP_PITCH];   // 192 x 65 x 4B = 49920 B

    int tid = threadIdx.x;
    int lane = tid & 63;
    int wv = tid >> 6;
    int blk = blockIdx.x;                 // 576 blocks
    int b = blk / (HW / 64);
    int p0 = (blk % (HW / 64)) * 64;

    // load phase: wave wv handles channels [wv*16, wv*16+16)
    for (int cc = 0; cc < 16; ++cc) {
        int ch = wv * 16 + cc;
        size_t gidx = ((size_t)(b * Cn + ch)) * HW + p0 + lane;
        float r = ref[gidx];
        float d = dist[gidx];
        float q = (r - d) * (r - d);
        lds[ch][lane] = r;
        lds[Cn + ch][lane] = d;
        lds[2 * Cn + ch][lane] = q;
        out_diff[gidx] = q;
    }
    __syncthreads();

    // store phase: coalesced NHWC writes
    for (int idx = tid; idx < 64 * C3; idx += 256) {
        int p = idx / C3;
        int c = idx % C3;
        packed[((size_t)(b * HW) + p0 + p) * C3 + c] = lds[c][p];
    }
}

// ---------------------------------------------------------------------------
// diff = (ref - dist)^2 -> f32 into d_out second half (fallback path only).
// ---------------------------------------------------------------------------
__global__ void diff_kernel(const float* __restrict__ ref,
                            const float* __restrict__ dist,
                            float* __restrict__ out_diff) {
    int i = blockIdx.x * blockDim.x + threadIdx.x;
    if (i < NFEAT) {
        float d = ref[i] - dist[i];
        out_diff[i] = d * d;
    }
}

// ---------------------------------------------------------------------------
// offset = conv3x3(ref, offset_w) + offset_b  -> f32 in workspace
// ---------------------------------------------------------------------------
__global__ void offset_kernel(const float* __restrict__ ref,
                              const float* __restrict__ ow,
                              const float* __restrict__ ob,
                              float* __restrict__ off) {
    int t = blockIdx.x * blockDim.x + threadIdx.x;
    if (t >= NOFF) return;
    int x = t % Wd;
    int y = (t / Wd) % Hd;
    int v = (t / HW) % 18;
    int b = t / (HW * 18);
    float acc = ob[v];
    const float* rb = ref + (size_t)b * (Cn * HW);
    const float* wb = ow + (size_t)v * (Cn * 9);
    for (int k = 0; k < 9; ++k) {
        int ky = k / 3, kx = k % 3;
        int yy = y - 1 + ky, xx = x - 1 + kx;
        if ((unsigned)yy < (unsigned)Hd && (unsigned)xx < (unsigned)Wd) {
            const float* rp = rb + yy * Wd + xx;
            const float* wp = wb + k;
#pragma unroll
            for (int c = 0; c < Cn; ++c)
                acc += rp[c * HW] * wp[c * 9];
        }
    }
    off[t] = acc;
}

// ---------------------------------------------------------------------------
// Transpose deform_w [O,192,3,3] -> wT[(k*192+c)*64 + o] f32.
// ---------------------------------------------------------------------------
__global__ void wt_kernel(const float* __restrict__ w, float* __restrict__ wt) {
    int t = blockIdx.x * blockDim.x + threadIdx.x;
    if (t >= C3 * KK * On) return;
    int o = t & 63;
    int kc = t >> 6;
    int c = kc % C3;
    int k = kc / C3;
    wt[t] = w[((size_t)o * C3 + c) * 9 + k];
}

// ===========================================================================
// FAST deform conv: gathers from NHWC packed (coalesced 256B reads).
// Block = 256 threads / 4 waves, 8 consecutive pixels.
// Phase 1: 72 (pixel,tap) tasks round-robin over waves; per task 12 coalesced
//          global loads (4 neighbors x 3 sections), bilinear combine, -> LDS.
// Phase 2: each lane accumulates 2 pixels x output o=lane over K=1728.
// ===========================================================================
__global__ __launch_bounds__(256) void deform_kernel(
        const float* __restrict__ packed,
        const float* __restrict__ off,     // ws
        const float* __restrict__ wt,      // ws
        const float* __restrict__ db,
        float* __restrict__ out) {
    __shared__ float s[8][C3 * KK];        // 8 x 1728 f32 = 55296 B

    int tid = threadIdx.x;
    int lane = tid & 63;
    int wv = tid >> 6;
    int blk = blockIdx.x;
    int p0 = blk * 8;
    int b = p0 / HW;                       // all 8 pixels share b (8 | HW)
    int pb = p0 - b * HW;                  // pixel index within image

    // ---- phase 1 ----
    for (int t = wv; t < 72; t += 4) {
        int pix = t & 7;
        int k = t >> 3;
        int pidx = pb + pix;               // y*Wd + x
        int x = pidx % Wd;
        int y = pidx / Wd;
        const float* op = off + ((size_t)(b * 18 + 2 * k)) * HW + pidx;
        float dy = op[0];
        float dx = op[HW];
        float py = (float)(y - 1 + k / 3) + dy;
        float px = (float)(x - 1 + k % 3) + dx;
        float fy = floorf(py), fx = floorf(px);
        int y0 = (int)fy, x0 = (int)fx;
        float ay = py - fy, ax = px - fx;
        float w00 = (1.f - ay) * (1.f - ax);
        float w01 = (1.f - ay) * ax;
        float w10 = ay * (1.f - ax);
        float w11 = ay * ax;
        float a0 = 0.f, a1 = 0.f, a2 = 0.f;
        int base = b * HW;
#define NB(yy, xx, wgt)                                                        \
        if ((unsigned)(yy) < (unsigned)Hd && (unsigned)(xx) < (unsigned)Wd) {  \
            const float* bp = packed + ((size_t)(base + (yy) * Wd + (xx))) * C3;\
            a0 += (wgt) * bp[lane];                                            \
            a1 += (wgt) * bp[Cn + lane];                                       \
            a2 += (wgt) * bp[2 * Cn + lane];                                   \
        }
        NB(y0,     x0,     w00)
        NB(y0,     x0 + 1, w01)
        NB(y0 + 1, x0,     w10)
        NB(y0 + 1, x0 + 1, w11)
#undef NB
        s[pix][k * C3 + lane] = a0;
        s[pix][k * C3 + Cn + lane] = a1;
        s[pix][k * C3 + 2 * Cn + lane] = a2;
    }
    __syncthreads();

    // ---- phase 2: 1728-deep dot, 2 pixels per lane ----
    int o = lane;
    float accA = db[o];
    float accB = accA;
    const float* sA = s[wv];
    const float* sB = s[wv + 4];
#pragma unroll 8
    for (int i = 0; i < C3 * KK; ++i) {
        float wf = wt[i * 64 + o];
        accA += sA[i] * wf;
        accB += sB[i] * wf;
    }
    accA = fmaxf(accA, 0.f);
    accB = fmaxf(accB, 0.f);

    int pA = p0 + wv;
    int pB = pA + 4;
    {
        int pi = pA - b * HW;
        out[((size_t)(b * On + o)) * HW + pi] = accA;
    }
    {
        int pi = pB - b * HW;
        out[((size_t)(b * On + o)) * HW + pi] = accB;
    }
}

// ===========================================================================
// Fallback deform (round-4 path, NCHW gathers) in case ws is small.
// ===========================================================================
__device__ __forceinline__ float bilin_f32(const float* pl,
                                           int y0, int x0, int y1, int x1,
                                           bool vy0, bool vx0, bool vy1, bool vx1,
                                           float w00, float w01, float w10, float w11) {
    float v00 = (vy0 && vx0) ? pl[y0 * Wd + x0] : 0.f;
    float v01 = (vy0 && vx1) ? pl[y0 * Wd + x1] : 0.f;
    float v10 = (vy1 && vx0) ? pl[y1 * Wd + x0] : 0.f;
    float v11 = (vy1 && vx1) ? pl[y1 * Wd + x1] : 0.f;
    return w00 * v00 + w01 * v01 + w10 * v10 + w11 * v11;
}

__global__ __launch_bounds__(256) void deform_slow(
        const float* __restrict__ ref,
        const float* __restrict__ dist,
        const float* __restrict__ diff,
        const float* __restrict__ off,
        const float* __restrict__ wt,
        const float* __restrict__ db,
        float* __restrict__ out) {
    __shared__ float s[8][C3 * KK];
    int tid = threadIdx.x;
    int lane = tid & 63;
    int wv = tid >> 6;
    int blk = blockIdx.x;
    for (int pp = 0; pp < 2; ++pp) {
        int pix = wv + pp * 4;
        int p = blk * 8 + pix;
        int x = p % Wd;
        int y = (p / Wd) % Hd;
        int b = p / HW;
        const float* offp = off + (size_t)b * (18 * HW) + y * Wd + x;
        const float* plr = ref  + ((size_t)b * Cn + lane) * HW;
        const float* pld = dist + ((size_t)b * Cn + lane) * HW;
        const float* plq = diff + ((size_t)b * Cn + lane) * HW;
        for (int k = 0; k < 9; ++k) {
            float dy = offp[(2 * k) * HW];
            float dx = offp[(2 * k + 1) * HW];
            float py = (float)(y - 1 + k / 3) + dy;
            float px = (float)(x - 1 + k % 3) + dx;
            float fy = floorf(py), fx = floorf(px);
            int y0 = (int)fy, x0 = (int)fx;
            float ay = py - fy, ax = px - fx;
            float w00 = (1.f - ay) * (1.f - ax);
            float w01 = (1.f - ay) * ax;
            float w10 = ay * (1.f - ax);
            float w11 = ay * ax;
            bool vy0 = (unsigned)y0 < (unsigned)Hd;
            bool vy1 = (unsigned)(y0 + 1) < (unsigned)Hd;
            bool vx0 = (unsigned)x0 < (unsigned)Wd;
            bool vx1 = (unsigned)(x0 + 1) < (unsigned)Wd;
            s[pix][k * C3 + lane] =
                bilin_f32(plr, y0, x0, y0 + 1, x0 + 1, vy0, vx0, vy1, vx1, w00, w01, w10, w11);
            s[pix][k * C3 + Cn + lane] =
                bilin_f32(pld, y0, x0, y0 + 1, x0 + 1, vy0, vx0, vy1, vx1, w00, w01, w10, w11);
            s[pix][k * C3 + 2 * Cn + lane] =
                bilin_f32(plq, y0, x0, y0 + 1, x0 + 1, vy0, vx0, vy1, vx1, w00, w01, w10, w11);
        }
    }
    __syncthreads();
    int o = lane;
    float accA = db[o];
    float accB = accA;
    const float* sA = s[wv];
    const float* sB = s[wv + 4];
#pragma unroll 8
    for (int i = 0; i < C3 * KK; ++i) {
        float wf = wt[i * 64 + o];
        accA += sA[i] * wf;
        accB += sB[i] * wf;
    }
    accA = fmaxf(accA, 0.f);
    accB = fmaxf(accB, 0.f);
    int pA = blk * 8 + wv;
    int pB = pA + 4;
    {
        int x = pA % Wd, y = (pA / Wd) % Hd, b = pA / HW;
        out[((size_t)b * On + o) * HW + y * Wd + x] = accA;
    }
    {
        int x = pB % Wd, y = (pB / Wd) % Hd, b = pB / HW;
        out[((size_t)b * On + o) * HW + y * Wd + x] = accB;
    }
}

// ---------------------------------------------------------------------------
extern "C" void kernel_launch(void* const* d_in, const int* in_sizes, int n_in,
                              void* d_out, int out_size, void* d_ws, size_t ws_size,
                              hipStream_t stream) {
    const float* ref  = (const float*)d_in[0];
    const float* dist = (const float*)d_in[1];
    const float* ow   = (const float*)d_in[2];
    const float* ob   = (const float*)d_in[3];
    const float* dw   = (const float*)d_in[4];
    const float* db   = (const float*)d_in[5];

    float* out = (float*)d_out;               // [feat | diff], each NFEAT f32

    float* ws_off = (float*)d_ws;             // NOFF f32
    float* ws_wt  = ws_off + NOFF;            // 110592 f32
    float* ws_pk  = ws_wt + C3 * KK * On;     // NPIX*192 f32 = 28.3 MB

    size_t need = ((size_t)NOFF + C3 * KK * On + (size_t)NPIX * C3) * sizeof(float);

    offset_kernel<<<(NOFF + 255) / 256, 256, 0, stream>>>(ref, ow, ob, ws_off);
    wt_kernel<<<(C3 * KK * On + 255) / 256, 256, 0, stream>>>(dw, ws_wt);

    if (ws_size >= need) {
        repack_kernel<<<Bn * (HW / 64), 256, 0, stream>>>(ref, dist, ws_pk, out + NFEAT);
        deform_kernel<<<NPIX / 8, 256, 0, stream>>>(ws_pk, ws_off, ws_wt, db, out);
    } else {
        diff_kernel<<<(NFEAT + 255) / 256, 256, 0, stream>>>(ref, dist, out + NFEAT);
        deform_slow<<<NPIX / 8, 256, 0, stream>>>(ref, dist, out + NFEAT,
                                                  ws_off, ws_wt, db, out);
    }
}

// Round 6
// 322.252 us; speedup vs baseline: 3.3098x; 2.0769x over previous
//
#include <hip/hip_runtime.h>
#include <hip/hip_bf16.h>

// Problem constants
#define Wd    96
#define Hd    96
#define HW    9216           // 96*96
#define Bn    4
#define Cn    64             // channels per section
#define C3    192            // 3*Cn
#define On    64             // out channels
#define KK    9              // 3x3 taps
#define NPIX  (Bn*HW)        // 36864
#define NFEAT (Bn*Cn*HW)     // 2359296 elements per output tensor
#define NOFF  (Bn*18*HW)     // 663552 offset elements
#define NWTB  (KK*6*4*512)   // 110592 bf16 frag-linear weights

typedef __attribute__((ext_vector_type(8))) short s8v;    // 8 bf16 (4 VGPRs)
typedef __attribute__((ext_vector_type(4))) float f4v;    // MFMA accum

// ===========================================================================
// repack: NCHW ref/dist -> NHWC packed[b][p][c] (c = ref|dist|diff, 192),
// fused diff computation; also writes diff (NCHW f32) to d_out second half.
// ===========================================================================
#define RP_PITCH 65
__global__ __launch_bounds__(256) void repack_kernel(
        const float* __restrict__ ref,
        const float* __restrict__ dist,
        float* __restrict__ packed,
        float* __restrict__ out_diff) {
    __shared__ float lds[C3][RP_PITCH];   // 192 x 65 x 4B = 49920 B

    int tid = threadIdx.x;
    int lane = tid & 63;
    int wv = tid >> 6;
    int blk = blockIdx.x;                 // 576 blocks
    int b = blk / (HW / 64);
    int p0 = (blk % (HW / 64)) * 64;

    for (int cc = 0; cc < 16; ++cc) {
        int ch = wv * 16 + cc;
        size_t gidx = ((size_t)(b * Cn + ch)) * HW + p0 + lane;
        float r = ref[gidx];
        float d = dist[gidx];
        float q = (r - d) * (r - d);
        lds[ch][lane] = r;
        lds[Cn + ch][lane] = d;
        lds[2 * Cn + ch][lane] = q;
        out_diff[gidx] = q;
    }
    __syncthreads();

    for (int idx = tid; idx < 64 * C3; idx += 256) {
        int p = idx / C3;
        int c = idx % C3;
        packed[((size_t)(b * HW) + p0 + p) * C3 + c] = lds[c][p];
    }
}

// ---------------------------------------------------------------------------
// offset = conv3x3(ref, offset_w) + offset_b  -> f32 in workspace
// ---------------------------------------------------------------------------
__global__ void offset_kernel(const float* __restrict__ ref,
                              const float* __restrict__ ow,
                              const float* __restrict__ ob,
                              float* __restrict__ off) {
    int t = blockIdx.x * blockDim.x + threadIdx.x;
    if (t >= NOFF) return;
    int x = t % Wd;
    int y = (t / Wd) % Hd;
    int v = (t / HW) % 18;
    int b = t / (HW * 18);
    float acc = ob[v];
    const float* rb = ref + (size_t)b * (Cn * HW);
    const float* wb = ow + (size_t)v * (Cn * 9);
    for (int k = 0; k < 9; ++k) {
        int ky = k / 3, kx = k % 3;
        int yy = y - 1 + ky, xx = x - 1 + kx;
        if ((unsigned)yy < (unsigned)Hd && (unsigned)xx < (unsigned)Wd) {
            const float* rp = rb + yy * Wd + xx;
            const float* wp = wb + k;
#pragma unroll
            for (int c = 0; c < Cn; ++c)
                acc += rp[c * HW] * wp[c * 9];
        }
    }
    off[t] = acc;
}

// ---------------------------------------------------------------------------
// wt_kernel: deform_w [O,192,3,3] f32 -> bf16 in MFMA B-frag-linear order.
// Element e = (((tap*6 + kc)*4 + nt)*64 + L)*8 + j holds
//   w[o = nt*16 + (L&15)][c = kc*32 + (L>>4)*8 + j][tap]
// so a wave's B-frag load is 64 lanes x 16 B contiguous.
// ---------------------------------------------------------------------------
__global__ void wt_kernel(const float* __restrict__ w,
                          __hip_bfloat16* __restrict__ wtb) {
    int e = blockIdx.x * blockDim.x + threadIdx.x;
    if (e >= NWTB) return;
    int j = e & 7;
    int L = (e >> 3) & 63;
    int nt = (e >> 9) & 3;
    int rest = e >> 11;           // 0..53
    int kc = rest % 6;
    int tap = rest / 6;
    int o = nt * 16 + (L & 15);
    int c = kc * 32 + (L >> 4) * 8 + j;
    wtb[e] = __float2bfloat16(w[((size_t)o * C3 + c) * 9 + tap]);
}

// ===========================================================================
// MFMA deform conv. Block = 256 thr / 4 waves, 32 pixels (M=32), N=64, K=1728
// processed tap-by-tap (9 x K=192). Per tap: gather A[32x192] bf16 into LDS
// in frag-linear order; 12 x mfma_f32_16x16x32_bf16 per wave; B-frags from
// global (L2-resident, frag-linear). Epilogue: bias+ReLU, LDS transpose,
// coalesced NCHW stores.
// LDS: 12 segs x 64 lanes x 16 B = 12288 B (reused as 64x33 f32 for epilogue).
// ===========================================================================
__global__ __launch_bounds__(256) void deform_mfma(
        const float* __restrict__ packed,
        const float* __restrict__ off,
        const __hip_bfloat16* __restrict__ wtb,
        const float* __restrict__ db,
        float* __restrict__ out) {
    __shared__ __align__(16) unsigned char smem[12 * 64 * 16];
    __hip_bfloat16* As16 = (__hip_bfloat16*)smem;     // frag-linear A
    const s8v* Ap = (const s8v*)smem;                 // frag reads
    float* Cs = (float*)smem;                         // epilogue 64x33 f32
    const s8v* Bp = (const s8v*)wtb;

    int tid = threadIdx.x;
    int L = tid & 63;
    int wv = tid >> 6;
    int p0 = blockIdx.x * 32;
    int b = p0 / HW;
    int pb = p0 - b * HW;                 // all 32 pixels in same image

    int mt = wv & 1;                      // MFMA M-half for this wave
    int nt0 = (wv >> 1) * 2;              // first of 2 N-tiles

    f4v acc0 = {0.f, 0.f, 0.f, 0.f};
    f4v acc1 = {0.f, 0.f, 0.f, 0.f};

    for (int t = 0; t < 9; ++t) {
        // ---- gather tap t: wave wv covers pixels [wv*8, wv*8+8) ----
#pragma unroll 2
        for (int pp = 0; pp < 8; ++pp) {
            int pix = wv * 8 + pp;        // 0..31
            int mtp = pix >> 4;
            int m = pix & 15;
            int pid = pb + pix;
            int x = pid % Wd;
            int y = pid / Wd;
            const float* op = off + ((size_t)(b * 18 + 2 * t)) * HW + pid;
            float dy = op[0];
            float dx = op[HW];
            float py = (float)(y - 1 + t / 3) + dy;
            float px = (float)(x - 1 + t % 3) + dx;
            float fy = floorf(py), fx = floorf(px);
            int y0 = (int)fy, x0 = (int)fx;
            float ay = py - fy, ax = px - fx;
            float w00 = (1.f - ay) * (1.f - ax);
            float w01 = (1.f - ay) * ax;
            float w10 = ay * (1.f - ax);
            float w11 = ay * ax;
            float a0 = 0.f, a1 = 0.f, a2 = 0.f;
            int base = b * HW;
#define NB(yy, xx, wgt)                                                        \
            if ((unsigned)(yy) < (unsigned)Hd && (unsigned)(xx) < (unsigned)Wd) { \
                const float* bp = packed + ((size_t)(base + (yy) * Wd + (xx))) * C3; \
                a0 += (wgt) * bp[L];                                           \
                a1 += (wgt) * bp[Cn + L];                                      \
                a2 += (wgt) * bp[2 * Cn + L];                                  \
            }
            NB(y0,     x0,     w00)
            NB(y0,     x0 + 1, w01)
            NB(y0 + 1, x0,     w10)
            NB(y0 + 1, x0 + 1, w11)
#undef NB
            // scatter 3 bf16 into frag-linear A
#pragma unroll
            for (int s2 = 0; s2 < 3; ++s2) {
                int c = s2 * 64 + L;
                int kc = c >> 5;
                int q = (c >> 3) & 3;
                int j = c & 7;
                int Lw = (q << 4) | m;
                float v = (s2 == 0) ? a0 : (s2 == 1) ? a1 : a2;
                As16[(((mtp * 6 + kc) * 64 + Lw) << 3) + j] = __float2bfloat16(v);
            }
        }
        __syncthreads();

        // ---- MFMA over this tap's K=192 (6 chunks of 32) ----
#pragma unroll
        for (int kc = 0; kc < 6; ++kc) {
            s8v a = Ap[(mt * 6 + kc) * 64 + L];
            s8v b0 = Bp[((t * 6 + kc) * 4 + nt0) * 64 + L];
            s8v b1 = Bp[((t * 6 + kc) * 4 + nt0 + 1) * 64 + L];
            acc0 = __builtin_amdgcn_mfma_f32_16x16x32_bf16(a, b0, acc0, 0, 0, 0);
            acc1 = __builtin_amdgcn_mfma_f32_16x16x32_bf16(a, b1, acc1, 0, 0, 0);
        }
        __syncthreads();
    }

    // ---- epilogue: bias + ReLU -> LDS [o][px] (pitch 33) -> coalesced out
    int n = L & 15;
    int q = L >> 4;
    {
        int o0 = nt0 * 16 + n;
        int o1 = (nt0 + 1) * 16 + n;
        float bi0 = db[o0];
        float bi1 = db[o1];
#pragma unroll
        for (int r = 0; r < 4; ++r) {
            int row = mt * 16 + q * 4 + r;
            Cs[o0 * 33 + row] = fmaxf(acc0[r] + bi0, 0.f);
            Cs[o1 * 33 + row] = fmaxf(acc1[r] + bi1, 0.f);
        }
    }
    __syncthreads();

#pragma unroll
    for (int i = 0; i < 8; ++i) {
        int idx = i * 256 + tid;
        int o = idx >> 5;
        int px = idx & 31;
        out[((size_t)(b * On + o)) * HW + pb + px] = Cs[o * 33 + px];
    }
}

// ---------------------------------------------------------------------------
extern "C" void kernel_launch(void* const* d_in, const int* in_sizes, int n_in,
                              void* d_out, int out_size, void* d_ws, size_t ws_size,
                              hipStream_t stream) {
    const float* ref  = (const float*)d_in[0];
    const float* dist = (const float*)d_in[1];
    const float* ow   = (const float*)d_in[2];
    const float* ob   = (const float*)d_in[3];
    const float* dw   = (const float*)d_in[4];
    const float* db   = (const float*)d_in[5];

    float* out = (float*)d_out;               // [feat | diff], each NFEAT f32

    float* ws_off = (float*)d_ws;                                   // 2 654 208 B
    __hip_bfloat16* ws_wtb = (__hip_bfloat16*)((char*)d_ws + (size_t)NOFF * 4);
    float* ws_pk  = (float*)((char*)d_ws + (size_t)NOFF * 4 + (size_t)NWTB * 2);

    offset_kernel<<<(NOFF + 255) / 256, 256, 0, stream>>>(ref, ow, ob, ws_off);
    wt_kernel<<<(NWTB + 255) / 256, 256, 0, stream>>>(dw, ws_wtb);
    repack_kernel<<<Bn * (HW / 64), 256, 0, stream>>>(ref, dist, ws_pk, out + NFEAT);
    deform_mfma<<<NPIX / 32, 256, 0, stream>>>(ws_pk, ws_off, ws_wtb, db, out);
}

// Round 7
// 260.392 us; speedup vs baseline: 4.0960x; 1.2376x over previous
//
#include <hip/hip_runtime.h>
#include <hip/hip_bf16.h>

// Problem constants
#define Wd    96
#define Hd    96
#define HW    9216           // 96*96
#define Bn    4
#define Cn    64             // channels per section
#define C3    192            // 3*Cn
#define On    64             // out channels
#define KK    9              // 3x3 taps
#define NPIX  (Bn*HW)        // 36864
#define NFEAT (Bn*Cn*HW)     // 2359296 elements per output tensor
#define NWTB  (KK*6*4*512)   // 110592 bf16 frag-linear deform weights
#define NWTB2 (18*2*64*8)    // 18432 bf16 frag-linear offset weights
#define APITCH 212           // deform A-LDS pitch (dwords, 16B-aligned rows)
#define OPITCH 68            // offset A-LDS pitch

typedef __attribute__((ext_vector_type(8))) short s8v;    // 8 bf16
typedef __attribute__((ext_vector_type(4))) float f4v;    // MFMA accum

__device__ __forceinline__ short f2bf(float x) {
    __hip_bfloat16 h = __float2bfloat16(x);
    return __builtin_bit_cast(short, h);
}

__device__ __forceinline__ s8v pack8(const float* p) {
    float4 u0 = *(const float4*)p;
    float4 u1 = *(const float4*)(p + 4);
    s8v r;
    r[0] = f2bf(u0.x); r[1] = f2bf(u0.y); r[2] = f2bf(u0.z); r[3] = f2bf(u0.w);
    r[4] = f2bf(u1.x); r[5] = f2bf(u1.y); r[6] = f2bf(u1.z); r[7] = f2bf(u1.w);
    return r;
}

// ===========================================================================
// repack: NCHW ref/dist -> NHWC packed[b][p][c] (c = ref|dist|diff, 192),
// fused diff; also writes diff (NCHW f32) to d_out second half.
// ===========================================================================
#define RP_PITCH 65
__global__ __launch_bounds__(256) void repack_kernel(
        const float* __restrict__ ref,
        const float* __restrict__ dist,
        float* __restrict__ packed,
        float* __restrict__ out_diff) {
    __shared__ float lds[C3][RP_PITCH];

    int tid = threadIdx.x;
    int lane = tid & 63;
    int wv = tid >> 6;
    int blk = blockIdx.x;
    int b = blk / (HW / 64);
    int p0 = (blk % (HW / 64)) * 64;

    for (int cc = 0; cc < 16; ++cc) {
        int ch = wv * 16 + cc;
        size_t gidx = ((size_t)(b * Cn + ch)) * HW + p0 + lane;
        float r = ref[gidx];
        float d = dist[gidx];
        float q = (r - d) * (r - d);
        lds[ch][lane] = r;
        lds[Cn + ch][lane] = d;
        lds[2 * Cn + ch][lane] = q;
        out_diff[gidx] = q;
    }
    __syncthreads();

    for (int idx = tid; idx < 64 * C3; idx += 256) {
        int p = idx / C3;
        int c = idx % C3;
        packed[((size_t)(b * HW) + p0 + p) * C3 + c] = lds[c][p];
    }
}

// ---------------------------------------------------------------------------
// wt_kernel: deform_w [O,192,3,3] -> bf16 MFMA B-frag-linear.
// e = (((tap*6+kc)*4+nt)*64+L)*8+j  ->  w[o=nt*16+(L&15)][c=kc*32+(L>>4)*8+j][tap]
// ---------------------------------------------------------------------------
__global__ void wt_kernel(const float* __restrict__ w,
                          __hip_bfloat16* __restrict__ wtb) {
    int e = blockIdx.x * blockDim.x + threadIdx.x;
    if (e >= NWTB) return;
    int j = e & 7;
    int L = (e >> 3) & 63;
    int nt = (e >> 9) & 3;
    int rest = e >> 11;
    int kc = rest % 6;
    int tap = rest / 6;
    int o = nt * 16 + (L & 15);
    int c = kc * 32 + (L >> 4) * 8 + j;
    wtb[e] = __float2bfloat16(w[((size_t)o * C3 + c) * 9 + tap]);
}

// ---------------------------------------------------------------------------
// wt2_kernel: offset_w [18,64,3,3] -> bf16 B-frag-linear, N padded to 32.
// e = ((kc2*2+nt)*64+L)*8+j  ->  v=nt*16+(L&15); k=kc2*32+(L>>4)*8+j;
//                                c=k&63; tap=k>>6;  0 if v>=18.
// ---------------------------------------------------------------------------
__global__ void wt2_kernel(const float* __restrict__ w,
                           __hip_bfloat16* __restrict__ wtb2) {
    int e = blockIdx.x * blockDim.x + threadIdx.x;
    if (e >= NWTB2) return;
    int j = e & 7;
    int L = (e >> 3) & 63;
    int nt = (e >> 9) & 1;
    int kc2 = e >> 10;            // 0..17
    int v = nt * 16 + (L & 15);
    int k = kc2 * 32 + ((L >> 4) & 3) * 8 + j;
    int c = k & 63;
    int tap = k >> 6;
    float val = (v < 18) ? w[((size_t)v * Cn + c) * 9 + tap] : 0.f;
    wtb2[e] = __float2bfloat16(val);
}

// ===========================================================================
// offset_mfma: offset conv via MFMA. Block = 256 thr / 4 waves, 64 px,
// N=32 (18 used), K=576 tap-by-tap. A staged as plain f32 LDS [64][OPITCH].
// Output: pixel-major offsets ws_off[p][18] (+bias, no relu).
// ===========================================================================
__global__ __launch_bounds__(256) void offset_mfma(
        const float* __restrict__ packed,
        const __hip_bfloat16* __restrict__ wtb2,
        const float* __restrict__ ob,
        float* __restrict__ off) {
    __shared__ __align__(16) float As[64 * OPITCH];   // 17408 B
    const s8v* Bp = (const s8v*)wtb2;

    int tid = threadIdx.x;
    int L = tid & 63;
    int wv = tid >> 6;
    // XCD swizzle: contiguous region per XCD
    int blk = blockIdx.x;
    int region = (blk & 7) * 72 + (blk >> 3);         // 576 blocks
    int p0 = region * 64;
    int b = p0 / HW;
    int pb = p0 - b * HW;

    f4v acc0 = {0.f, 0.f, 0.f, 0.f};
    f4v acc1 = {0.f, 0.f, 0.f, 0.f};

    for (int t = 0; t < 9; ++t) {
        int ty = t / 3, tx = t % 3;
        // gather: wave wv covers pixels [wv*16, wv*16+16), lane = channel
        for (int i = 0; i < 16; ++i) {
            int pix = wv * 16 + i;
            int pid = pb + pix;
            int y = pid / Wd, x = pid % Wd;
            int yy = y - 1 + ty, xx = x - 1 + tx;
            float v = 0.f;
            if ((unsigned)yy < (unsigned)Hd && (unsigned)xx < (unsigned)Wd)
                v = packed[((size_t)(b * HW + yy * Wd + xx)) * C3 + L];
            As[pix * OPITCH + L] = v;
        }
        __syncthreads();

#pragma unroll
        for (int kc = 0; kc < 2; ++kc) {
            s8v a = pack8(&As[(wv * 16 + (L & 15)) * OPITCH + kc * 32 + (L >> 4) * 8]);
            int kc2 = t * 2 + kc;
            s8v b0 = Bp[(kc2 * 2 + 0) * 64 + L];
            s8v b1 = Bp[(kc2 * 2 + 1) * 64 + L];
            acc0 = __builtin_amdgcn_mfma_f32_16x16x32_bf16(a, b0, acc0, 0, 0, 0);
            acc1 = __builtin_amdgcn_mfma_f32_16x16x32_bf16(a, b1, acc1, 0, 0, 0);
        }
        __syncthreads();
    }

    // epilogue: C row = pixel (q*4+r within m-tile wv), col = v
    int n = L & 15;
    int q = L >> 4;
    float bias0 = ob[n];
#pragma unroll
    for (int r = 0; r < 4; ++r) {
        int pl = wv * 16 + q * 4 + r;
        off[(size_t)(p0 + pl) * 18 + n] = acc0[r] + bias0;
    }
    if (n < 2) {
        float bias1 = ob[16 + n];
#pragma unroll
        for (int r = 0; r < 4; ++r) {
            int pl = wv * 16 + q * 4 + r;
            off[(size_t)(p0 + pl) * 18 + 16 + n] = acc1[r] + bias1;
        }
    }
}

// ===========================================================================
// deform_mfma: 32 px/block, N=64, K=1728 tap-by-tap. Gather -> plain f32
// LDS [32][APITCH] (conflict-free writes); frag built at read (b128 + cvt).
// XCD-swizzled blocks for L2 locality. Epilogue: bias+ReLU, LDS transpose.
// ===========================================================================
__global__ __launch_bounds__(256) void deform_mfma(
        const float* __restrict__ packed,
        const float* __restrict__ off,     // [NPIX][18]
        const __hip_bfloat16* __restrict__ wtb,
        const float* __restrict__ db,
        float* __restrict__ out) {
    __shared__ __align__(16) char smem[32 * APITCH * 4];  // 27136 B
    float* As = (float*)smem;
    float* Cs = (float*)smem;              // epilogue 64x33 f32 (8448 B)
    const s8v* Bp = (const s8v*)wtb;

    int tid = threadIdx.x;
    int L = tid & 63;
    int wv = tid >> 6;
    // XCD swizzle: 1152 blocks -> 8 contiguous regions of 144 blocks
    int blk = blockIdx.x;
    int region = (blk & 7) * 144 + (blk >> 3);
    int p0 = region * 32;
    int b = p0 / HW;
    int pb = p0 - b * HW;

    int mt = wv & 1;
    int nt0 = (wv >> 1) * 2;

    f4v acc0 = {0.f, 0.f, 0.f, 0.f};
    f4v acc1 = {0.f, 0.f, 0.f, 0.f};

    for (int t = 0; t < 9; ++t) {
        // ---- gather tap t: wave wv covers pixels [wv*8, wv*8+8) ----
        for (int pp = 0; pp < 8; ++pp) {
            int pix = wv * 8 + pp;
            int pid = pb + pix;
            int x = pid % Wd;
            int y = pid / Wd;
            const float* op = off + (size_t)(b * HW + pid) * 18 + 2 * t;
            float dy = op[0];
            float dx = op[1];
            float py = (float)(y - 1 + t / 3) + dy;
            float px = (float)(x - 1 + t % 3) + dx;
            float fy = floorf(py), fx = floorf(px);
            int y0 = (int)fy, x0 = (int)fx;
            float ay = py - fy, ax = px - fx;
            float w00 = (1.f - ay) * (1.f - ax);
            float w01 = (1.f - ay) * ax;
            float w10 = ay * (1.f - ax);
            float w11 = ay * ax;
            float a0 = 0.f, a1 = 0.f, a2 = 0.f;
            int base = b * HW;
#define NB(yy, xx, wgt)                                                        \
            if ((unsigned)(yy) < (unsigned)Hd && (unsigned)(xx) < (unsigned)Wd) { \
                const float* bp = packed + ((size_t)(base + (yy) * Wd + (xx))) * C3; \
                a0 += (wgt) * bp[L];                                           \
                a1 += (wgt) * bp[Cn + L];                                      \
                a2 += (wgt) * bp[2 * Cn + L];                                  \
            }
            NB(y0,     x0,     w00)
            NB(y0,     x0 + 1, w01)
            NB(y0 + 1, x0,     w10)
            NB(y0 + 1, x0 + 1, w11)
#undef NB
            float* row = As + pix * APITCH;
            row[L] = a0;
            row[Cn + L] = a1;
            row[2 * Cn + L] = a2;
        }
        __syncthreads();

        // ---- MFMA: 6 K-chunks of 32 ----
#pragma unroll
        for (int kc = 0; kc < 6; ++kc) {
            s8v a = pack8(&As[(mt * 16 + (L & 15)) * APITCH + kc * 32 + (L >> 4) * 8]);
            s8v b0 = Bp[((t * 6 + kc) * 4 + nt0) * 64 + L];
            s8v b1 = Bp[((t * 6 + kc) * 4 + nt0 + 1) * 64 + L];
            acc0 = __builtin_amdgcn_mfma_f32_16x16x32_bf16(a, b0, acc0, 0, 0, 0);
            acc1 = __builtin_amdgcn_mfma_f32_16x16x32_bf16(a, b1, acc1, 0, 0, 0);
        }
        __syncthreads();
    }

    // ---- epilogue: bias + ReLU -> LDS [o][px] (pitch 33) -> coalesced out
    int n = L & 15;
    int q = L >> 4;
    {
        int o0 = nt0 * 16 + n;
        int o1 = (nt0 + 1) * 16 + n;
        float bi0 = db[o0];
        float bi1 = db[o1];
#pragma unroll
        for (int r = 0; r < 4; ++r) {
            int row = mt * 16 + q * 4 + r;
            Cs[o0 * 33 + row] = fmaxf(acc0[r] + bi0, 0.f);
            Cs[o1 * 33 + row] = fmaxf(acc1[r] + bi1, 0.f);
        }
    }
    __syncthreads();

#pragma unroll
    for (int i = 0; i < 8; ++i) {
        int idx = i * 256 + tid;
        int o = idx >> 5;
        int px = idx & 31;
        out[((size_t)(b * On + o)) * HW + pb + px] = Cs[o * 33 + px];
    }
}

// ---------------------------------------------------------------------------
extern "C" void kernel_launch(void* const* d_in, const int* in_sizes, int n_in,
                              void* d_out, int out_size, void* d_ws, size_t ws_size,
                              hipStream_t stream) {
    const float* ref  = (const float*)d_in[0];
    const float* dist = (const float*)d_in[1];
    const float* ow   = (const float*)d_in[2];
    const float* ob   = (const float*)d_in[3];
    const float* dw   = (const float*)d_in[4];
    const float* db   = (const float*)d_in[5];

    float* out = (float*)d_out;               // [feat | diff], each NFEAT f32

    // ws layout: offsets [NPIX][18] f32 | deform wtb bf16 | offset wtb2 bf16 | packed
    float* ws_off = (float*)d_ws;
    __hip_bfloat16* ws_wtb  = (__hip_bfloat16*)((char*)d_ws + (size_t)NPIX * 18 * 4);
    __hip_bfloat16* ws_wtb2 = ws_wtb + NWTB;
    float* ws_pk = (float*)((char*)d_ws + (size_t)NPIX * 18 * 4
                            + (size_t)(NWTB + NWTB2) * 2);

    repack_kernel<<<Bn * (HW / 64), 256, 0, stream>>>(ref, dist, ws_pk, out + NFEAT);
    wt_kernel<<<(NWTB + 255) / 256, 256, 0, stream>>>(dw, ws_wtb);
    wt2_kernel<<<(NWTB2 + 255) / 256, 256, 0, stream>>>(ow, ws_wtb2);
    offset_mfma<<<NPIX / 64, 256, 0, stream>>>(ws_pk, ws_wtb2, ob, ws_off);
    deform_mfma<<<NPIX / 32, 256, 0, stream>>>(ws_pk, ws_off, ws_wtb, db, out);
}

// Round 8
// 209.687 us; speedup vs baseline: 5.0865x; 1.2418x over previous
//
#include <hip/hip_runtime.h>
#include <hip/hip_bf16.h>

// Problem constants
#define Wd    96
#define Hd    96
#define HW    9216           // 96*96
#define Bn    4
#define Cn    64             // channels per section
#define C3    192            // 3*Cn
#define On    64             // out channels
#define NPIX  (Bn*HW)        // 36864
#define NFEAT (Bn*Cn*HW)     // 2359296 elements per output tensor
#define NWTB  (9*6*4*512)    // 110592 bf16 frag-linear deform weights
#define NWTB2 (18*2*64*8)    // 18432 bf16 frag-linear offset weights

typedef __attribute__((ext_vector_type(8))) short s8v;    // 8 bf16 / ushort8
typedef __attribute__((ext_vector_type(4))) float f4v;    // MFMA accum
typedef __hip_bfloat16 bf16;

__device__ __forceinline__ float bfs2f(short s) {
    unsigned u = ((unsigned)(unsigned short)s) << 16;
    return __builtin_bit_cast(float, u);
}
__device__ __forceinline__ short f2bfs(float x) {
    return __builtin_bit_cast(short, __float2bfloat16(x));
}

// ===========================================================================
// repack: NCHW ref/dist -> bf16 NHWC packed[b][p][c] (c = ref|dist|diff),
// fused diff; diff (NCHW f32) to d_out second half.
// ===========================================================================
#define RP_PITCH 65
__global__ __launch_bounds__(256) void repack_kernel(
        const float* __restrict__ ref,
        const float* __restrict__ dist,
        unsigned int* __restrict__ packed,    // [NPIX][96] bf16-pairs
        float* __restrict__ out_diff) {
    __shared__ float lds[C3][RP_PITCH];

    int tid = threadIdx.x;
    int lane = tid & 63;
    int wv = tid >> 6;
    int blk = blockIdx.x;
    int b = blk / (HW / 64);
    int p0 = (blk % (HW / 64)) * 64;

    for (int cc = 0; cc < 16; ++cc) {
        int ch = wv * 16 + cc;
        size_t g = ((size_t)(b * Cn + ch)) * HW + p0 + lane;
        float r = ref[g];
        float d = dist[g];
        float q = (r - d) * (r - d);
        lds[ch][lane] = r;
        lds[Cn + ch][lane] = d;
        lds[2 * Cn + ch][lane] = q;
        out_diff[g] = q;
    }
    __syncthreads();

    for (int i = tid; i < 64 * 96; i += 256) {
        int p = i / 96;
        int cp = i % 96;
        unsigned lo = (unsigned)(unsigned short)f2bfs(lds[2 * cp][p]);
        unsigned hi = (unsigned)(unsigned short)f2bfs(lds[2 * cp + 1][p]);
        packed[((size_t)(b * HW) + p0 + p) * 96 + cp] = lo | (hi << 16);
    }
}

// ---------------------------------------------------------------------------
// wt_kernel: deform_w [O,192,3,3] -> bf16 MFMA frag-linear (A-operand, M=o).
// e = (((tap*6+kc)*4+mt)*64+L)*8+j -> w[o=mt*16+(L&15)][c=kc*32+(L>>4)*8+j][tap]
// ---------------------------------------------------------------------------
__global__ void wt_kernel(const float* __restrict__ w,
                          bf16* __restrict__ wtb) {
    int e = blockIdx.x * blockDim.x + threadIdx.x;
    if (e >= NWTB) return;
    int j = e & 7;
    int L = (e >> 3) & 63;
    int mt = (e >> 9) & 3;
    int rest = e >> 11;
    int kc = rest % 6;
    int tap = rest / 6;
    int o = mt * 16 + (L & 15);
    int c = kc * 32 + (L >> 4) * 8 + j;
    wtb[e] = __float2bfloat16(w[((size_t)o * C3 + c) * 9 + tap]);
}

// ---------------------------------------------------------------------------
// wt2_kernel: offset_w [18,64,3,3] -> bf16 frag-linear (A-operand, M=v pad 32).
// ---------------------------------------------------------------------------
__global__ void wt2_kernel(const float* __restrict__ w,
                           bf16* __restrict__ wtb2) {
    int e = blockIdx.x * blockDim.x + threadIdx.x;
    if (e >= NWTB2) return;
    int j = e & 7;
    int L = (e >> 3) & 63;
    int mt = (e >> 9) & 1;
    int kc2 = e >> 10;            // 0..17 = t*2+kc
    int v = mt * 16 + (L & 15);
    int k = kc2 * 32 + ((L >> 4) & 3) * 8 + j;
    int c = k & 63;
    int tap = k >> 6;
    float val = (v < 18) ? w[((size_t)v * Cn + c) * 9 + tap] : 0.f;
    wtb2[e] = __float2bfloat16(val);
}

// ===========================================================================
// offset_mfma: M=v(32,18 used), N=16 px/wave, K=576. No LDS, no barriers.
// Gather lands directly in B-frag registers. Output off[p][18] f32.
// ===========================================================================
__global__ __launch_bounds__(256) void offset_mfma(
        const bf16* __restrict__ packed,
        const bf16* __restrict__ wtb2,
        const float* __restrict__ ob,
        float* __restrict__ off) {
    int tid = threadIdx.x;
    int L = tid & 63;
    int wv = tid >> 6;
    int px = L & 15;
    int lg = L >> 4;
    int blk = blockIdx.x;
    int region = (blk & 7) * 72 + (blk >> 3);         // 576 blocks, XCD swizzle
    int p0 = region * 64 + wv * 16;
    int b = p0 / HW;
    int pb = p0 - b * HW;
    int pid = pb + px;
    int x = pid % Wd, y = pid / Wd;

    const s8v* Ap = (const s8v*)wtb2;
    const s8v* pkb = (const s8v*)packed + (size_t)b * HW * 24;

    f4v acc0 = {0.f, 0.f, 0.f, 0.f};
    f4v acc1 = {0.f, 0.f, 0.f, 0.f};

#pragma unroll 1
    for (int t = 0; t < 9; ++t) {
        int yy = y - 1 + t / 3;
        int xx = x - 1 + t % 3;
        bool val = (unsigned)yy < (unsigned)Hd && (unsigned)xx < (unsigned)Wd;
        int yc = val ? yy : 0;
        int xc = val ? xx : 0;
        const s8v* q = pkb + (yc * Wd + xc) * 24;
        short msk = val ? (short)-1 : (short)0;
#pragma unroll
        for (int kc = 0; kc < 2; ++kc) {
            s8v u = q[kc * 4 + lg];
            s8v bfrag = u & msk;
            s8v a0 = Ap[((t * 2 + kc) * 2 + 0) * 64 + L];
            s8v a1 = Ap[((t * 2 + kc) * 2 + 1) * 64 + L];
            acc0 = __builtin_amdgcn_mfma_f32_16x16x32_bf16(a0, bfrag, acc0, 0, 0, 0);
            acc1 = __builtin_amdgcn_mfma_f32_16x16x32_bf16(a1, bfrag, acc1, 0, 0, 0);
        }
    }

    // epilogue: D col = px, row = v-in-tile = lg*4+r
    float* op = off + (size_t)(p0 + px) * 18;
#pragma unroll
    for (int r = 0; r < 4; ++r) {
        int v = lg * 4 + r;
        op[v] = acc0[r] + ob[v];
    }
    if (lg == 0) {
#pragma unroll
        for (int r = 0; r < 2; ++r)
            op[16 + r] = acc1[r] + ob[16 + r];
    }
}

// ===========================================================================
// deform_mfma: M=o(64), N=16 px/wave, K=1728. No LDS, no barriers.
// Bilinear gather lands directly in B-frag registers (lane L: pixel L&15,
// channels (L>>4)*8..+8 of each 32-chunk). Weights (A) frag-linear from L2.
// ===========================================================================
__global__ __launch_bounds__(256) void deform_mfma(
        const bf16* __restrict__ packed,
        const float* __restrict__ off,     // [NPIX][18]
        const bf16* __restrict__ wtb,
        const float* __restrict__ db,
        float* __restrict__ out) {
    int tid = threadIdx.x;
    int L = tid & 63;
    int wv = tid >> 6;
    int px = L & 15;
    int lg = L >> 4;
    int blk = blockIdx.x;
    int region = (blk & 7) * 72 + (blk >> 3);         // 576 blocks, XCD swizzle
    int p0 = region * 64 + wv * 16;
    int b = p0 / HW;
    int pb = p0 - b * HW;
    int pid = pb + px;
    int x = pid % Wd, y = pid / Wd;

    const s8v* Ap = (const s8v*)wtb;
    const s8v* pkb = (const s8v*)packed + (size_t)b * HW * 24;
    const float* offp = off + (size_t)(p0 + px) * 18;

    // prefetch all 9 taps' (dy,dx) for this lane's pixel
    float2 o2a[9];
#pragma unroll
    for (int t = 0; t < 9; ++t)
        o2a[t] = *(const float2*)(offp + 2 * t);

    f4v acc[4];
    acc[0] = acc[1] = acc[2] = acc[3] = (f4v){0.f, 0.f, 0.f, 0.f};

#pragma unroll 1
    for (int t = 0; t < 9; ++t) {
        float py = (float)(y - 1 + t / 3) + o2a[t].x;
        float pxs = (float)(x - 1 + t % 3) + o2a[t].y;
        float fy = floorf(py), fx = floorf(pxs);
        int y0 = (int)fy, x0 = (int)fx;
        int y1 = y0 + 1, x1 = x0 + 1;
        float ay = py - fy, ax = pxs - fx;
        bool vy0 = (unsigned)y0 < (unsigned)Hd;
        bool vy1 = (unsigned)y1 < (unsigned)Hd;
        bool vx0 = (unsigned)x0 < (unsigned)Wd;
        bool vx1 = (unsigned)x1 < (unsigned)Wd;
        float W00 = (vy0 && vx0) ? (1.f - ay) * (1.f - ax) : 0.f;
        float W01 = (vy0 && vx1) ? (1.f - ay) * ax : 0.f;
        float W10 = (vy1 && vx0) ? ay * (1.f - ax) : 0.f;
        float W11 = (vy1 && vx1) ? ay * ax : 0.f;
        int y0c = min(max(y0, 0), Hd - 1), y1c = min(max(y1, 0), Hd - 1);
        int x0c = min(max(x0, 0), Wd - 1), x1c = min(max(x1, 0), Wd - 1);
        const s8v* q00 = pkb + (y0c * Wd + x0c) * 24;
        const s8v* q01 = pkb + (y0c * Wd + x1c) * 24;
        const s8v* q10 = pkb + (y1c * Wd + x0c) * 24;
        const s8v* q11 = pkb + (y1c * Wd + x1c) * 24;
#pragma unroll
        for (int kc = 0; kc < 6; ++kc) {
            int idx = kc * 4 + lg;
            s8v u00 = q00[idx];
            s8v u01 = q01[idx];
            s8v u10 = q10[idx];
            s8v u11 = q11[idx];
            s8v bfrag;
#pragma unroll
            for (int j = 0; j < 8; ++j) {
                float v = W00 * bfs2f(u00[j]) + W01 * bfs2f(u01[j])
                        + W10 * bfs2f(u10[j]) + W11 * bfs2f(u11[j]);
                bfrag[j] = f2bfs(v);
            }
#pragma unroll
            for (int mt = 0; mt < 4; ++mt) {
                s8v a = Ap[((t * 6 + kc) * 4 + mt) * 64 + L];
                acc[mt] = __builtin_amdgcn_mfma_f32_16x16x32_bf16(a, bfrag, acc[mt], 0, 0, 0);
            }
        }
    }

    // epilogue: D col = px, row(o within tile) = lg*4+r; 4x64B segs per store
#pragma unroll
    for (int mt = 0; mt < 4; ++mt) {
#pragma unroll
        for (int r = 0; r < 4; ++r) {
            int o = mt * 16 + lg * 4 + r;
            out[((size_t)(b * On + o)) * HW + pb + px] =
                fmaxf(acc[mt][r] + db[o], 0.f);
        }
    }
}

// ---------------------------------------------------------------------------
extern "C" void kernel_launch(void* const* d_in, const int* in_sizes, int n_in,
                              void* d_out, int out_size, void* d_ws, size_t ws_size,
                              hipStream_t stream) {
    const float* ref  = (const float*)d_in[0];
    const float* dist = (const float*)d_in[1];
    const float* ow   = (const float*)d_in[2];
    const float* ob   = (const float*)d_in[3];
    const float* dw   = (const float*)d_in[4];
    const float* db   = (const float*)d_in[5];

    float* out = (float*)d_out;               // [feat | diff], each NFEAT f32

    // ws: off [NPIX][18] f32 | wtb bf16 | wtb2 bf16 | packed bf16 [NPIX][192]
    float* ws_off = (float*)d_ws;
    bf16* ws_wtb  = (bf16*)((char*)d_ws + (size_t)NPIX * 18 * 4);
    bf16* ws_wtb2 = ws_wtb + NWTB;
    bf16* ws_pk   = ws_wtb2 + NWTB2;

    repack_kernel<<<Bn * (HW / 64), 256, 0, stream>>>(
        ref, dist, (unsigned int*)ws_pk, out + NFEAT);
    wt_kernel<<<(NWTB + 255) / 256, 256, 0, stream>>>(dw, ws_wtb);
    wt2_kernel<<<(NWTB2 + 255) / 256, 256, 0, stream>>>(ow, ws_wtb2);
    offset_mfma<<<NPIX / 64, 256, 0, stream>>>(ws_pk, ws_wtb2, ob, ws_off);
    deform_mfma<<<NPIX / 64, 256, 0, stream>>>(ws_pk, ws_off, ws_wtb, db, out);
}

// Round 9
// 165.050 us; speedup vs baseline: 6.4621x; 1.2704x over previous
//
#include <hip/hip_runtime.h>
#include <hip/hip_bf16.h>

// Problem constants
#define Wd    96
#define Hd    96
#define HW    9216           // 96*96
#define Bn    4
#define Cn    64             // channels per section
#define C3    192            // 3*Cn
#define On    64             // out channels
#define NPIX  (Bn*HW)        // 36864
#define NFEAT (Bn*Cn*HW)     // 2359296 elements per output tensor
#define NWTB  (9*6*4*512)    // 110592 bf16 frag-linear deform weights
#define NWTB2 (18*2*64*8)    // 18432 bf16 frag-linear offset weights

typedef __attribute__((ext_vector_type(8))) short s8v;    // 8 bf16
typedef __attribute__((ext_vector_type(4))) unsigned int u4v;
typedef __attribute__((ext_vector_type(4))) float f4v;    // MFMA accum
typedef __hip_bfloat16 bf16;

__device__ __forceinline__ short f2bfs(float x) {
    return __builtin_bit_cast(short, __float2bfloat16(x));
}
__device__ __forceinline__ float blo(unsigned u) {
    return __builtin_bit_cast(float, u << 16);
}
__device__ __forceinline__ float bhi(unsigned u) {
    return __builtin_bit_cast(float, u & 0xffff0000u);
}
__device__ __forceinline__ unsigned packbf(float lo, float hi) {
    unsigned a = (unsigned)(unsigned short)f2bfs(lo);
    unsigned b = (unsigned)(unsigned short)f2bfs(hi);
    return a | (b << 16);
}

// ===========================================================================
// repack: NCHW ref/dist -> bf16 NHWC packed[b][p][c] (c = ref|dist|diff),
// fused diff; diff (NCHW f32) to d_out second half.
// ===========================================================================
#define RP_PITCH 65
__global__ __launch_bounds__(256) void repack_kernel(
        const float* __restrict__ ref,
        const float* __restrict__ dist,
        unsigned int* __restrict__ packed,    // [NPIX][96] bf16-pairs
        float* __restrict__ out_diff) {
    __shared__ float lds[C3][RP_PITCH];

    int tid = threadIdx.x;
    int lane = tid & 63;
    int wv = tid >> 6;
    int blk = blockIdx.x;
    int b = blk / (HW / 64);
    int p0 = (blk % (HW / 64)) * 64;

    for (int cc = 0; cc < 16; ++cc) {
        int ch = wv * 16 + cc;
        size_t g = ((size_t)(b * Cn + ch)) * HW + p0 + lane;
        float r = ref[g];
        float d = dist[g];
        float q = (r - d) * (r - d);
        lds[ch][lane] = r;
        lds[Cn + ch][lane] = d;
        lds[2 * Cn + ch][lane] = q;
        out_diff[g] = q;
    }
    __syncthreads();

    for (int i = tid; i < 64 * 96; i += 256) {
        int p = i / 96;
        int cp = i % 96;
        unsigned lo = (unsigned)(unsigned short)f2bfs(lds[2 * cp][p]);
        unsigned hi = (unsigned)(unsigned short)f2bfs(lds[2 * cp + 1][p]);
        packed[((size_t)(b * HW) + p0 + p) * 96 + cp] = lo | (hi << 16);
    }
}

// ---------------------------------------------------------------------------
// wt_kernel: deform_w [O,192,3,3] -> bf16 MFMA frag-linear (A-operand, M=o).
// e = (((tap*6+kc)*4+mt)*64+L)*8+j -> w[o=mt*16+(L&15)][c=kc*32+(L>>4)*8+j][tap]
// ---------------------------------------------------------------------------
__global__ void wt_kernel(const float* __restrict__ w,
                          bf16* __restrict__ wtb) {
    int e = blockIdx.x * blockDim.x + threadIdx.x;
    if (e >= NWTB) return;
    int j = e & 7;
    int L = (e >> 3) & 63;
    int mt = (e >> 9) & 3;
    int rest = e >> 11;
    int kc = rest % 6;
    int tap = rest / 6;
    int o = mt * 16 + (L & 15);
    int c = kc * 32 + (L >> 4) * 8 + j;
    wtb[e] = __float2bfloat16(w[((size_t)o * C3 + c) * 9 + tap]);
}

// ---------------------------------------------------------------------------
// wt2_kernel: offset_w [18,64,3,3] -> bf16 frag-linear (A-operand, M=v pad 32).
// ---------------------------------------------------------------------------
__global__ void wt2_kernel(const float* __restrict__ w,
                           bf16* __restrict__ wtb2) {
    int e = blockIdx.x * blockDim.x + threadIdx.x;
    if (e >= NWTB2) return;
    int j = e & 7;
    int L = (e >> 3) & 63;
    int mt = (e >> 9) & 1;
    int kc2 = e >> 10;            // 0..17 = t*2+kc
    int v = mt * 16 + (L & 15);
    int k = kc2 * 32 + ((L >> 4) & 3) * 8 + j;
    int c = k & 63;
    int tap = k >> 6;
    float val = (v < 18) ? w[((size_t)v * Cn + c) * 9 + tap] : 0.f;
    wtb2[e] = __float2bfloat16(val);
}

// ===========================================================================
// offset_mfma: M=v(32,18 used), N=16 px/wave, K=576. 64-thr blocks, no LDS.
// Software-pipelined: next tap's gather issued while current tap computes.
// ===========================================================================
__global__ __launch_bounds__(64) void offset_mfma(
        const bf16* __restrict__ packed,
        const bf16* __restrict__ wtb2,
        const float* __restrict__ ob,
        float* __restrict__ off) {
    int L = threadIdx.x;
    int px = L & 15;
    int lg = L >> 4;
    int blk = blockIdx.x;
    int region = (blk & 7) * 288 + (blk >> 3);        // 2304 blocks, XCD swizzle
    int p0 = region * 16;
    int b = p0 / HW;
    int pb = p0 - b * HW;
    int pid = pb + px;
    int x = pid % Wd, y = pid / Wd;

    const s8v* Ap = (const s8v*)wtb2;
    const char* pkb = (const char*)packed + (size_t)b * HW * (C3 * 2);

    f4v acc0 = {0.f, 0.f, 0.f, 0.f};
    f4v acc1 = {0.f, 0.f, 0.f, 0.f};

    s8v rawo[2][2];
    short msk[2];

    // prologue: tap 0
    {
        int yy = y - 1, xx = x - 1;
        bool val = (unsigned)yy < (unsigned)Hd && (unsigned)xx < (unsigned)Wd;
        int oc = ((val ? yy : 0) * Wd + (val ? xx : 0)) * (C3 * 2);
        msk[0] = val ? (short)-1 : (short)0;
        rawo[0][0] = *(const s8v*)(pkb + oc + (0 * 4 + lg) * 16);
        rawo[0][1] = *(const s8v*)(pkb + oc + (1 * 4 + lg) * 16);
    }

#pragma unroll
    for (int t = 0; t < 9; ++t) {
        if (t < 8) {
            int tn = t + 1;
            int yy = y - 1 + tn / 3, xx = x - 1 + tn % 3;
            bool val = (unsigned)yy < (unsigned)Hd && (unsigned)xx < (unsigned)Wd;
            int oc = ((val ? yy : 0) * Wd + (val ? xx : 0)) * (C3 * 2);
            msk[tn & 1] = val ? (short)-1 : (short)0;
            rawo[tn & 1][0] = *(const s8v*)(pkb + oc + (0 * 4 + lg) * 16);
            rawo[tn & 1][1] = *(const s8v*)(pkb + oc + (1 * 4 + lg) * 16);
        }
        short m = msk[t & 1];
#pragma unroll
        for (int kc = 0; kc < 2; ++kc) {
            s8v bfrag = rawo[t & 1][kc] & m;
            s8v a0 = Ap[((t * 2 + kc) * 2 + 0) * 64 + L];
            s8v a1 = Ap[((t * 2 + kc) * 2 + 1) * 64 + L];
            acc0 = __builtin_amdgcn_mfma_f32_16x16x32_bf16(a0, bfrag, acc0, 0, 0, 0);
            acc1 = __builtin_amdgcn_mfma_f32_16x16x32_bf16(a1, bfrag, acc1, 0, 0, 0);
        }
    }

    // epilogue: D col = px, row = v-in-tile = lg*4+r
    float* op = off + (size_t)(p0 + px) * 18;
#pragma unroll
    for (int r = 0; r < 4; ++r) {
        int v = lg * 4 + r;
        op[v] = acc0[r] + ob[v];
    }
    if (lg == 0) {
#pragma unroll
        for (int r = 0; r < 2; ++r)
            op[16 + r] = acc1[r] + ob[16 + r];
    }
}

// ===========================================================================
// deform_mfma: M=o(64), N=16 px/wave, K=1728. 64-thr blocks, no LDS.
// Half-tap software pipeline: 12 gather loads (3 kc x 4 neighbors) for
// half h+1 in flight while half h computes (bilinear + 12 MFMA).
// ===========================================================================
struct Ctx {
    int o00, o01, o10, o11;
    float W00, W01, W10, W11;
};

__device__ __forceinline__ Ctx mkctx(int t, int y, int x, float2 o2) {
    Ctx c;
    float py = (float)(y - 1 + t / 3) + o2.x;
    float pxs = (float)(x - 1 + t % 3) + o2.y;
    float fy = floorf(py), fx = floorf(pxs);
    int y0 = (int)fy, x0 = (int)fx;
    int y1 = y0 + 1, x1 = x0 + 1;
    float ay = py - fy, ax = pxs - fx;
    bool vy0 = (unsigned)y0 < (unsigned)Hd;
    bool vy1 = (unsigned)y1 < (unsigned)Hd;
    bool vx0 = (unsigned)x0 < (unsigned)Wd;
    bool vx1 = (unsigned)x1 < (unsigned)Wd;
    c.W00 = (vy0 && vx0) ? (1.f - ay) * (1.f - ax) : 0.f;
    c.W01 = (vy0 && vx1) ? (1.f - ay) * ax : 0.f;
    c.W10 = (vy1 && vx0) ? ay * (1.f - ax) : 0.f;
    c.W11 = (vy1 && vx1) ? ay * ax : 0.f;
    int y0c = min(max(y0, 0), Hd - 1), y1c = min(max(y1, 0), Hd - 1);
    int x0c = min(max(x0, 0), Wd - 1), x1c = min(max(x1, 0), Wd - 1);
    c.o00 = (y0c * Wd + x0c) * (C3 * 2);
    c.o01 = (y0c * Wd + x1c) * (C3 * 2);
    c.o10 = (y1c * Wd + x0c) * (C3 * 2);
    c.o11 = (y1c * Wd + x1c) * (C3 * 2);
    return c;
}

__global__ __launch_bounds__(64) void deform_mfma(
        const bf16* __restrict__ packed,
        const float* __restrict__ off,     // [NPIX][18]
        const bf16* __restrict__ wtb,
        const float* __restrict__ db,
        float* __restrict__ out) {
    int L = threadIdx.x;
    int px = L & 15;
    int lg = L >> 4;
    int blk = blockIdx.x;
    int region = (blk & 7) * 288 + (blk >> 3);        // 2304 blocks, XCD swizzle
    int p0 = region * 16;
    int b = p0 / HW;
    int pb = p0 - b * HW;
    int pid = pb + px;
    int x = pid % Wd, y = pid / Wd;

    const s8v* Ap = (const s8v*)wtb;
    const char* pkb = (const char*)packed + (size_t)b * HW * (C3 * 2);
    const float* offp = off + (size_t)(p0 + px) * 18;

    float2 o2a[9];
#pragma unroll
    for (int t = 0; t < 9; ++t)
        o2a[t] = *(const float2*)(offp + 2 * t);

    f4v acc[4];
    acc[0] = acc[1] = acc[2] = acc[3] = (f4v){0.f, 0.f, 0.f, 0.f};

    Ctx ctx[2];
    s8v raw[2][12];         // [buf][neighbor*3 + i], i = kc within half

    // prologue: tap 0, half 0 (kc 0..2)
    ctx[0] = mkctx(0, y, x, o2a[0]);
#pragma unroll
    for (int i = 0; i < 3; ++i) {
        raw[0][0 * 3 + i] = *(const s8v*)(pkb + ctx[0].o00 + (i * 4 + lg) * 16);
        raw[0][1 * 3 + i] = *(const s8v*)(pkb + ctx[0].o01 + (i * 4 + lg) * 16);
        raw[0][2 * 3 + i] = *(const s8v*)(pkb + ctx[0].o10 + (i * 4 + lg) * 16);
        raw[0][3 * 3 + i] = *(const s8v*)(pkb + ctx[0].o11 + (i * 4 + lg) * 16);
    }

#pragma unroll
    for (int h = 0; h < 18; ++h) {
        int t = h >> 1;
        int kb = (h & 1) * 3;
        int cbuf = h & 1;
        // ---- issue next half's loads ----
        if (h < 17) {
            int hn = h + 1;
            int tn = hn >> 1;
            int kbn = (hn & 1) * 3;
            if ((hn & 1) == 0)
                ctx[tn & 1] = mkctx(tn, y, x, o2a[tn]);
            const Ctx cn = ctx[tn & 1];
#pragma unroll
            for (int i = 0; i < 3; ++i) {
                int kc = kbn + i;
                raw[hn & 1][0 * 3 + i] = *(const s8v*)(pkb + cn.o00 + (kc * 4 + lg) * 16);
                raw[hn & 1][1 * 3 + i] = *(const s8v*)(pkb + cn.o01 + (kc * 4 + lg) * 16);
                raw[hn & 1][2 * 3 + i] = *(const s8v*)(pkb + cn.o10 + (kc * 4 + lg) * 16);
                raw[hn & 1][3 * 3 + i] = *(const s8v*)(pkb + cn.o11 + (kc * 4 + lg) * 16);
            }
        }
        // ---- compute current half ----
        const Ctx cc = ctx[t & 1];
#pragma unroll
        for (int i = 0; i < 3; ++i) {
            int kc = kb + i;
            u4v u00 = __builtin_bit_cast(u4v, raw[cbuf][0 * 3 + i]);
            u4v u01 = __builtin_bit_cast(u4v, raw[cbuf][1 * 3 + i]);
            u4v u10 = __builtin_bit_cast(u4v, raw[cbuf][2 * 3 + i]);
            u4v u11 = __builtin_bit_cast(u4v, raw[cbuf][3 * 3 + i]);
            u4v bu;
#pragma unroll
            for (int p = 0; p < 4; ++p) {
                float vlo = cc.W00 * blo(u00[p]) + cc.W01 * blo(u01[p])
                          + cc.W10 * blo(u10[p]) + cc.W11 * blo(u11[p]);
                float vhi = cc.W00 * bhi(u00[p]) + cc.W01 * bhi(u01[p])
                          + cc.W10 * bhi(u10[p]) + cc.W11 * bhi(u11[p]);
                bu[p] = packbf(vlo, vhi);
            }
            s8v bfrag = __builtin_bit_cast(s8v, bu);
#pragma unroll
            for (int mt = 0; mt < 4; ++mt) {
                s8v a = Ap[((t * 6 + kc) * 4 + mt) * 64 + L];
                acc[mt] = __builtin_amdgcn_mfma_f32_16x16x32_bf16(a, bfrag, acc[mt], 0, 0, 0);
            }
        }
    }

    // epilogue: D col = px, row(o within tile) = lg*4+r
#pragma unroll
    for (int mt = 0; mt < 4; ++mt) {
#pragma unroll
        for (int r = 0; r < 4; ++r) {
            int o = mt * 16 + lg * 4 + r;
            out[((size_t)(b * On + o)) * HW + pb + px] =
                fmaxf(acc[mt][r] + db[o], 0.f);
        }
    }
}

// ---------------------------------------------------------------------------
extern "C" void kernel_launch(void* const* d_in, const int* in_sizes, int n_in,
                              void* d_out, int out_size, void* d_ws, size_t ws_size,
                              hipStream_t stream) {
    const float* ref  = (const float*)d_in[0];
    const float* dist = (const float*)d_in[1];
    const float* ow   = (const float*)d_in[2];
    const float* ob   = (const float*)d_in[3];
    const float* dw   = (const float*)d_in[4];
    const float* db   = (const float*)d_in[5];

    float* out = (float*)d_out;               // [feat | diff], each NFEAT f32

    // ws: off [NPIX][18] f32 | wtb bf16 | wtb2 bf16 | packed bf16 [NPIX][192]
    float* ws_off = (float*)d_ws;
    bf16* ws_wtb  = (bf16*)((char*)d_ws + (size_t)NPIX * 18 * 4);
    bf16* ws_wtb2 = ws_wtb + NWTB;
    bf16* ws_pk   = ws_wtb2 + NWTB2;

    repack_kernel<<<Bn * (HW / 64), 256, 0, stream>>>(
        ref, dist, (unsigned int*)ws_pk, out + NFEAT);
    wt_kernel<<<(NWTB + 255) / 256, 256, 0, stream>>>(dw, ws_wtb);
    wt2_kernel<<<(NWTB2 + 255) / 256, 256, 0, stream>>>(ow, ws_wtb2);
    offset_mfma<<<NPIX / 16, 64, 0, stream>>>(ws_pk, ws_wtb2, ob, ws_off);
    deform_mfma<<<NPIX / 16, 64, 0, stream>>>(ws_pk, ws_off, ws_wtb, db, out);
}

// Round 10
// 164.547 us; speedup vs baseline: 6.4819x; 1.0031x over previous
//
#include <hip/hip_runtime.h>
#include <hip/hip_bf16.h>

// Problem constants
#define Wd    96
#define Hd    96
#define HW    9216           // 96*96
#define Bn    4
#define Cn    64             // channels per section
#define C3    192            // 3*Cn
#define On    64             // out channels
#define NPIX  (Bn*HW)        // 36864
#define NFEAT (Bn*Cn*HW)     // 2359296 elements per output tensor
#define NWTB  (9*6*4*512)    // 110592 bf16 frag-linear deform weights
#define NWTB2 (18*2*64*8)    // 18432 bf16 frag-linear offset weights

typedef __attribute__((ext_vector_type(8))) short s8v;    // 8 bf16
typedef __attribute__((ext_vector_type(4))) unsigned int u4v;
typedef __attribute__((ext_vector_type(4))) float f4v;    // MFMA accum
typedef __hip_bfloat16 bf16;

__device__ __forceinline__ short f2bfs(float x) {
    return __builtin_bit_cast(short, __float2bfloat16(x));
}
__device__ __forceinline__ float blo(unsigned u) {
    return __builtin_bit_cast(float, u << 16);
}
__device__ __forceinline__ float bhi(unsigned u) {
    return __builtin_bit_cast(float, u & 0xffff0000u);
}
__device__ __forceinline__ unsigned packbf(float lo, float hi) {
    unsigned a = (unsigned)(unsigned short)f2bfs(lo);
    unsigned b = (unsigned)(unsigned short)f2bfs(hi);
    return a | (b << 16);
}

// ===========================================================================
// repack: NCHW ref/dist -> bf16 NHWC packed[b][p][c] (c = ref|dist|diff),
// fused diff; diff (NCHW f32) to d_out second half.
// LDS [px][193]: conflict-free writes (stride 193%32=1) and 2-way-free reads.
// ===========================================================================
__global__ __launch_bounds__(256) void repack_kernel(
        const float* __restrict__ ref,
        const float* __restrict__ dist,
        unsigned int* __restrict__ packed,    // [NPIX][96] bf16-pairs
        float* __restrict__ out_diff) {
    __shared__ float lds[64][193];            // 49408 B

    int tid = threadIdx.x;
    int lane = tid & 63;
    int wv = tid >> 6;
    int blk = blockIdx.x;
    int b = blk / (HW / 64);
    int p0 = (blk % (HW / 64)) * 64;

    for (int cc = 0; cc < 16; ++cc) {
        int ch = wv * 16 + cc;
        size_t g = ((size_t)(b * Cn + ch)) * HW + p0 + lane;
        float r = ref[g];
        float d = dist[g];
        float q = (r - d) * (r - d);
        lds[lane][ch] = r;
        lds[lane][Cn + ch] = d;
        lds[lane][2 * Cn + ch] = q;
        out_diff[g] = q;
    }
    __syncthreads();

    for (int i = tid; i < 64 * 96; i += 256) {
        int p = i / 96;
        int cp = i % 96;
        unsigned lo = (unsigned)(unsigned short)f2bfs(lds[p][2 * cp]);
        unsigned hi = (unsigned)(unsigned short)f2bfs(lds[p][2 * cp + 1]);
        packed[((size_t)(b * HW) + p0 + p) * 96 + cp] = lo | (hi << 16);
    }
}

// ---------------------------------------------------------------------------
// wts_kernel: both weight repacks in one launch.
//  deform_w [O,192,3,3] -> wtb frag-linear:
//   e = (((tap*6+kc)*4+mt)*64+L)*8+j -> w[o=mt*16+(L&15)][c=kc*32+(L>>4)*8+j][tap]
//  offset_w [18,64,3,3] -> wtb2 frag-linear (M=v pad 32).
// ---------------------------------------------------------------------------
__global__ void wts_kernel(const float* __restrict__ dw,
                           const float* __restrict__ ow,
                           bf16* __restrict__ wtb,
                           bf16* __restrict__ wtb2) {
    int e = blockIdx.x * blockDim.x + threadIdx.x;
    if (e < NWTB) {
        int j = e & 7;
        int L = (e >> 3) & 63;
        int mt = (e >> 9) & 3;
        int rest = e >> 11;
        int kc = rest % 6;
        int tap = rest / 6;
        int o = mt * 16 + (L & 15);
        int c = kc * 32 + (L >> 4) * 8 + j;
        wtb[e] = __float2bfloat16(dw[((size_t)o * C3 + c) * 9 + tap]);
    } else if (e < NWTB + NWTB2) {
        int e2 = e - NWTB;
        int j = e2 & 7;
        int L = (e2 >> 3) & 63;
        int mt = (e2 >> 9) & 1;
        int kc2 = e2 >> 10;           // 0..17 = t*2+kc
        int v = mt * 16 + (L & 15);
        int k = kc2 * 32 + ((L >> 4) & 3) * 8 + j;
        int c = k & 63;
        int tap = k >> 6;
        float val = (v < 18) ? ow[((size_t)v * Cn + c) * 9 + tap] : 0.f;
        wtb2[e2] = __float2bfloat16(val);
    }
}

// ===========================================================================
// offset_mfma: M=v(32,18 used), N=16 px/wave, K=576. 64-thr blocks, no LDS.
// Software-pipelined: next tap's B gather AND A frags issued during compute.
// ===========================================================================
__global__ __launch_bounds__(64, 2) void offset_mfma(
        const bf16* __restrict__ packed,
        const bf16* __restrict__ wtb2,
        const float* __restrict__ ob,
        float* __restrict__ off) {
    int L = threadIdx.x;
    int px = L & 15;
    int lg = L >> 4;
    int blk = blockIdx.x;
    int region = (blk & 7) * 288 + (blk >> 3);        // 2304 blocks, XCD swizzle
    int p0 = region * 16;
    int b = p0 / HW;
    int pb = p0 - b * HW;
    int pid = pb + px;
    int x = pid % Wd, y = pid / Wd;

    const s8v* Ap = (const s8v*)wtb2;
    const char* pkb = (const char*)packed + (size_t)b * HW * (C3 * 2);

    f4v acc0 = {0.f, 0.f, 0.f, 0.f};
    f4v acc1 = {0.f, 0.f, 0.f, 0.f};

    s8v rawo[2][2];
    s8v arw[2][4];
    short msk[2];

    // prologue: tap 0
    {
        int yy = y - 1, xx = x - 1;
        bool val = (unsigned)yy < (unsigned)Hd && (unsigned)xx < (unsigned)Wd;
        int oc = ((val ? yy : 0) * Wd + (val ? xx : 0)) * (C3 * 2);
        msk[0] = val ? (short)-1 : (short)0;
        rawo[0][0] = *(const s8v*)(pkb + oc + (0 * 4 + lg) * 16);
        rawo[0][1] = *(const s8v*)(pkb + oc + (1 * 4 + lg) * 16);
#pragma unroll
        for (int kc = 0; kc < 2; ++kc) {
            arw[0][kc * 2 + 0] = Ap[((0 * 2 + kc) * 2 + 0) * 64 + L];
            arw[0][kc * 2 + 1] = Ap[((0 * 2 + kc) * 2 + 1) * 64 + L];
        }
    }

#pragma unroll
    for (int t = 0; t < 9; ++t) {
        if (t < 8) {
            int tn = t + 1;
            int yy = y - 1 + tn / 3, xx = x - 1 + tn % 3;
            bool val = (unsigned)yy < (unsigned)Hd && (unsigned)xx < (unsigned)Wd;
            int oc = ((val ? yy : 0) * Wd + (val ? xx : 0)) * (C3 * 2);
            msk[tn & 1] = val ? (short)-1 : (short)0;
            rawo[tn & 1][0] = *(const s8v*)(pkb + oc + (0 * 4 + lg) * 16);
            rawo[tn & 1][1] = *(const s8v*)(pkb + oc + (1 * 4 + lg) * 16);
#pragma unroll
            for (int kc = 0; kc < 2; ++kc) {
                arw[tn & 1][kc * 2 + 0] = Ap[((tn * 2 + kc) * 2 + 0) * 64 + L];
                arw[tn & 1][kc * 2 + 1] = Ap[((tn * 2 + kc) * 2 + 1) * 64 + L];
            }
        }
        short m = msk[t & 1];
#pragma unroll
        for (int kc = 0; kc < 2; ++kc) {
            s8v bfrag = rawo[t & 1][kc] & m;
            acc0 = __builtin_amdgcn_mfma_f32_16x16x32_bf16(arw[t & 1][kc * 2 + 0], bfrag, acc0, 0, 0, 0);
            acc1 = __builtin_amdgcn_mfma_f32_16x16x32_bf16(arw[t & 1][kc * 2 + 1], bfrag, acc1, 0, 0, 0);
        }
    }

    // epilogue: D col = px, row = v-in-tile = lg*4+r
    float* op = off + (size_t)(p0 + px) * 18;
#pragma unroll
    for (int r = 0; r < 4; ++r) {
        int v = lg * 4 + r;
        op[v] = acc0[r] + ob[v];
    }
    if (lg == 0) {
#pragma unroll
        for (int r = 0; r < 2; ++r)
            op[16 + r] = acc1[r] + ob[16 + r];
    }
}

// ===========================================================================
// deform_mfma: M=o(64), N=16 px/wave, K=1728. 64-thr blocks, no LDS.
// Half-tap software pipeline: 12 gather loads (3 kc x 4 neighbors) for
// half h+1 in flight while half h computes (bilinear + 12 MFMA).
// __launch_bounds__(64,2): VGPR cap 256 so raw[2][12] stays in registers
// (grid limits occupancy to ~2.25 waves/SIMD anyway — registers are free).
// ===========================================================================
struct Ctx {
    int o00, o01, o10, o11;
    float W00, W01, W10, W11;
};

__device__ __forceinline__ Ctx mkctx(int t, int y, int x, float2 o2) {
    Ctx c;
    float py = (float)(y - 1 + t / 3) + o2.x;
    float pxs = (float)(x - 1 + t % 3) + o2.y;
    float fy = floorf(py), fx = floorf(pxs);
    int y0 = (int)fy, x0 = (int)fx;
    int y1 = y0 + 1, x1 = x0 + 1;
    float ay = py - fy, ax = pxs - fx;
    bool vy0 = (unsigned)y0 < (unsigned)Hd;
    bool vy1 = (unsigned)y1 < (unsigned)Hd;
    bool vx0 = (unsigned)x0 < (unsigned)Wd;
    bool vx1 = (unsigned)x1 < (unsigned)Wd;
    c.W00 = (vy0 && vx0) ? (1.f - ay) * (1.f - ax) : 0.f;
    c.W01 = (vy0 && vx1) ? (1.f - ay) * ax : 0.f;
    c.W10 = (vy1 && vx0) ? ay * (1.f - ax) : 0.f;
    c.W11 = (vy1 && vx1) ? ay * ax : 0.f;
    int y0c = min(max(y0, 0), Hd - 1), y1c = min(max(y1, 0), Hd - 1);
    int x0c = min(max(x0, 0), Wd - 1), x1c = min(max(x1, 0), Wd - 1);
    c.o00 = (y0c * Wd + x0c) * (C3 * 2);
    c.o01 = (y0c * Wd + x1c) * (C3 * 2);
    c.o10 = (y1c * Wd + x0c) * (C3 * 2);
    c.o11 = (y1c * Wd + x1c) * (C3 * 2);
    return c;
}

__global__ __launch_bounds__(64, 2) void deform_mfma(
        const bf16* __restrict__ packed,
        const float* __restrict__ off,     // [NPIX][18]
        const bf16* __restrict__ wtb,
        const float* __restrict__ db,
        float* __restrict__ out) {
    int L = threadIdx.x;
    int px = L & 15;
    int lg = L >> 4;
    int blk = blockIdx.x;
    int region = (blk & 7) * 288 + (blk >> 3);        // 2304 blocks, XCD swizzle
    int p0 = region * 16;
    int b = p0 / HW;
    int pb = p0 - b * HW;
    int pid = pb + px;
    int x = pid % Wd, y = pid / Wd;

    const s8v* Ap = (const s8v*)wtb;
    const char* pkb = (const char*)packed + (size_t)b * HW * (C3 * 2);
    const float* offp = off + (size_t)(p0 + px) * 18;

    float2 o2a[9];
#pragma unroll
    for (int t = 0; t < 9; ++t)
        o2a[t] = *(const float2*)(offp + 2 * t);

    f4v acc[4];
    acc[0] = acc[1] = acc[2] = acc[3] = (f4v){0.f, 0.f, 0.f, 0.f};

    Ctx ctx[2];
    s8v raw[2][12];         // [buf][neighbor*3 + i], i = kc within half

    // prologue: tap 0, half 0 (kc 0..2)
    ctx[0] = mkctx(0, y, x, o2a[0]);
#pragma unroll
    for (int i = 0; i < 3; ++i) {
        raw[0][0 * 3 + i] = *(const s8v*)(pkb + ctx[0].o00 + (i * 4 + lg) * 16);
        raw[0][1 * 3 + i] = *(const s8v*)(pkb + ctx[0].o01 + (i * 4 + lg) * 16);
        raw[0][2 * 3 + i] = *(const s8v*)(pkb + ctx[0].o10 + (i * 4 + lg) * 16);
        raw[0][3 * 3 + i] = *(const s8v*)(pkb + ctx[0].o11 + (i * 4 + lg) * 16);
    }

#pragma unroll
    for (int h = 0; h < 18; ++h) {
        int t = h >> 1;
        int kb = (h & 1) * 3;
        int cbuf = h & 1;
        // ---- issue next half's loads ----
        if (h < 17) {
            int hn = h + 1;
            int tn = hn >> 1;
            int kbn = (hn & 1) * 3;
            if ((hn & 1) == 0)
                ctx[tn & 1] = mkctx(tn, y, x, o2a[tn]);
            const Ctx cn = ctx[tn & 1];
#pragma unroll
            for (int i = 0; i < 3; ++i) {
                int kc = kbn + i;
                raw[hn & 1][0 * 3 + i] = *(const s8v*)(pkb + cn.o00 + (kc * 4 + lg) * 16);
                raw[hn & 1][1 * 3 + i] = *(const s8v*)(pkb + cn.o01 + (kc * 4 + lg) * 16);
                raw[hn & 1][2 * 3 + i] = *(const s8v*)(pkb + cn.o10 + (kc * 4 + lg) * 16);
                raw[hn & 1][3 * 3 + i] = *(const s8v*)(pkb + cn.o11 + (kc * 4 + lg) * 16);
            }
        }
        // ---- compute current half ----
        const Ctx cc = ctx[t & 1];
#pragma unroll
        for (int i = 0; i < 3; ++i) {
            int kc = kb + i;
            u4v u00 = __builtin_bit_cast(u4v, raw[cbuf][0 * 3 + i]);
            u4v u01 = __builtin_bit_cast(u4v, raw[cbuf][1 * 3 + i]);
            u4v u10 = __builtin_bit_cast(u4v, raw[cbuf][2 * 3 + i]);
            u4v u11 = __builtin_bit_cast(u4v, raw[cbuf][3 * 3 + i]);
            u4v bu;
#pragma unroll
            for (int p = 0; p < 4; ++p) {
                float vlo = cc.W00 * blo(u00[p]) + cc.W01 * blo(u01[p])
                          + cc.W10 * blo(u10[p]) + cc.W11 * blo(u11[p]);
                float vhi = cc.W00 * bhi(u00[p]) + cc.W01 * bhi(u01[p])
                          + cc.W10 * bhi(u10[p]) + cc.W11 * bhi(u11[p]);
                bu[p] = packbf(vlo, vhi);
            }
            s8v bfrag = __builtin_bit_cast(s8v, bu);
#pragma unroll
            for (int mt = 0; mt < 4; ++mt) {
                s8v a = Ap[((t * 6 + kc) * 4 + mt) * 64 + L];
                acc[mt] = __builtin_amdgcn_mfma_f32_16x16x32_bf16(a, bfrag, acc[mt], 0, 0, 0);
            }
        }
    }

    // epilogue: D col = px, row(o within tile) = lg*4+r
#pragma unroll
    for (int mt = 0; mt < 4; ++mt) {
#pragma unroll
        for (int r = 0; r < 4; ++r) {
            int o = mt * 16 + lg * 4 + r;
            out[((size_t)(b * On + o)) * HW + pb + px] =
                fmaxf(acc[mt][r] + db[o], 0.f);
        }
    }
}

// ---------------------------------------------------------------------------
extern "C" void kernel_launch(void* const* d_in, const int* in_sizes, int n_in,
                              void* d_out, int out_size, void* d_ws, size_t ws_size,
                              hipStream_t stream) {
    const float* ref  = (const float*)d_in[0];
    const float* dist = (const float*)d_in[1];
    const float* ow   = (const float*)d_in[2];
    const float* ob   = (const float*)d_in[3];
    const float* dw   = (const float*)d_in[4];
    const float* db   = (const float*)d_in[5];

    float* out = (float*)d_out;               // [feat | diff], each NFEAT f32

    // ws: off [NPIX][18] f32 | wtb bf16 | wtb2 bf16 | packed bf16 [NPIX][192]
    float* ws_off = (float*)d_ws;
    bf16* ws_wtb  = (bf16*)((char*)d_ws + (size_t)NPIX * 18 * 4);
    bf16* ws_wtb2 = ws_wtb + NWTB;
    bf16* ws_pk   = ws_wtb2 + NWTB2;

    repack_kernel<<<Bn * (HW / 64), 256, 0, stream>>>(
        ref, dist, (unsigned int*)ws_pk, out + NFEAT);
    wts_kernel<<<(NWTB + NWTB2 + 255) / 256, 256, 0, stream>>>(
        dw, ow, ws_wtb, ws_wtb2);
    offset_mfma<<<NPIX / 16, 64, 0, stream>>>(ws_pk, ws_wtb2, ob, ws_off);
    deform_mfma<<<NPIX / 16, 64, 0, stream>>>(ws_pk, ws_off, ws_wtb, db, out);
}

// Round 11
// 162.478 us; speedup vs baseline: 6.5644x; 1.0127x over previous
//
#include <hip/hip_runtime.h>
#include <hip/hip_bf16.h>

// Problem constants
#define Wd    96
#define Hd    96
#define HW    9216           // 96*96
#define Bn    4
#define Cn    64             // channels per section
#define C3    192            // 3*Cn
#define On    64             // out channels
#define NPIX  (Bn*HW)        // 36864
#define NFEAT (Bn*Cn*HW)     // 2359296 elements per output tensor
#define NWTB  (9*6*4*512)    // 110592 bf16 frag-linear deform weights
#define NWTB2 (18*2*64*8)    // 18432 bf16 frag-linear offset weights

typedef __attribute__((ext_vector_type(8))) short s8v;    // 8 bf16
typedef __attribute__((ext_vector_type(4))) unsigned int u4v;
typedef __attribute__((ext_vector_type(4))) float f4v;    // MFMA accum
typedef __hip_bfloat16 bf16;

__device__ __forceinline__ short f2bfs(float x) {
    return __builtin_bit_cast(short, __float2bfloat16(x));
}
__device__ __forceinline__ float blo(unsigned u) {
    return __builtin_bit_cast(float, u << 16);
}
__device__ __forceinline__ float bhi(unsigned u) {
    return __builtin_bit_cast(float, u & 0xffff0000u);
}
__device__ __forceinline__ unsigned packbf(float lo, float hi) {
    unsigned a = (unsigned)(unsigned short)f2bfs(lo);
    unsigned b = (unsigned)(unsigned short)f2bfs(hi);
    return a | (b << 16);
}

// ===========================================================================
// repack: NCHW ref/dist -> bf16 NHWC packed[b][p][c] (c = ref|dist|diff),
// fused diff; diff (NCHW f32) to d_out second half.
// ===========================================================================
__global__ __launch_bounds__(256) void repack_kernel(
        const float* __restrict__ ref,
        const float* __restrict__ dist,
        unsigned int* __restrict__ packed,    // [NPIX][96] bf16-pairs
        float* __restrict__ out_diff) {
    __shared__ float lds[64][193];            // 49408 B

    int tid = threadIdx.x;
    int lane = tid & 63;
    int wv = tid >> 6;
    int blk = blockIdx.x;
    int b = blk / (HW / 64);
    int p0 = (blk % (HW / 64)) * 64;

    for (int cc = 0; cc < 16; ++cc) {
        int ch = wv * 16 + cc;
        size_t g = ((size_t)(b * Cn + ch)) * HW + p0 + lane;
        float r = ref[g];
        float d = dist[g];
        float q = (r - d) * (r - d);
        lds[lane][ch] = r;
        lds[lane][Cn + ch] = d;
        lds[lane][2 * Cn + ch] = q;
        out_diff[g] = q;
    }
    __syncthreads();

    for (int i = tid; i < 64 * 96; i += 256) {
        int p = i / 96;
        int cp = i % 96;
        unsigned lo = (unsigned)(unsigned short)f2bfs(lds[p][2 * cp]);
        unsigned hi = (unsigned)(unsigned short)f2bfs(lds[p][2 * cp + 1]);
        packed[((size_t)(b * HW) + p0 + p) * 96 + cp] = lo | (hi << 16);
    }
}

// ---------------------------------------------------------------------------
// wts_kernel: both weight repacks in one launch (frag-linear bf16).
// ---------------------------------------------------------------------------
__global__ void wts_kernel(const float* __restrict__ dw,
                           const float* __restrict__ ow,
                           bf16* __restrict__ wtb,
                           bf16* __restrict__ wtb2) {
    int e = blockIdx.x * blockDim.x + threadIdx.x;
    if (e < NWTB) {
        int j = e & 7;
        int L = (e >> 3) & 63;
        int mt = (e >> 9) & 3;
        int rest = e >> 11;
        int kc = rest % 6;
        int tap = rest / 6;
        int o = mt * 16 + (L & 15);
        int c = kc * 32 + (L >> 4) * 8 + j;
        wtb[e] = __float2bfloat16(dw[((size_t)o * C3 + c) * 9 + tap]);
    } else if (e < NWTB + NWTB2) {
        int e2 = e - NWTB;
        int j = e2 & 7;
        int L = (e2 >> 3) & 63;
        int mt = (e2 >> 9) & 1;
        int kc2 = e2 >> 10;           // 0..17 = t*2+kc
        int v = mt * 16 + (L & 15);
        int k = kc2 * 32 + ((L >> 4) & 3) * 8 + j;
        int c = k & 63;
        int tap = k >> 6;
        float val = (v < 18) ? ow[((size_t)v * Cn + c) * 9 + tap] : 0.f;
        wtb2[e2] = __float2bfloat16(val);
    }
}

// ===========================================================================
// offset_mfma: M=v(32,18 used), N=16 px, K=576 split over 3 waves (3 taps
// each), LDS reduction. 192-thr blocks -> 6.75 waves/SIMD latency hiding.
// ===========================================================================
__global__ __launch_bounds__(192) void offset_mfma(
        const bf16* __restrict__ packed,
        const bf16* __restrict__ wtb2,
        const float* __restrict__ ob,
        float* __restrict__ off) {
    __shared__ float red[2][64 * 9];          // 4608 B

    int tid = threadIdx.x;
    int L = tid & 63;
    int wv = tid / 64;                        // 0..2
    int px = L & 15;
    int lg = L >> 4;
    int blk = blockIdx.x;
    int region = (blk & 7) * 288 + (blk >> 3);        // 2304 blocks, XCD swizzle
    int p0 = region * 16;
    int b = p0 / HW;
    int pb = p0 - b * HW;
    int pid = pb + px;
    int x = pid % Wd, y = pid / Wd;
    int tbase = wv * 3;

    const s8v* Ap = (const s8v*)wtb2;
    const char* pkb = (const char*)packed + (size_t)b * HW * (C3 * 2);

    f4v acc0 = {0.f, 0.f, 0.f, 0.f};
    f4v acc1 = {0.f, 0.f, 0.f, 0.f};

    s8v rawo[2][2];
    short msk[2];

    // prologue: first tap of this wave
    {
        int t = tbase;
        int yy = y - 1 + t / 3, xx = x - 1 + t % 3;
        bool val = (unsigned)yy < (unsigned)Hd && (unsigned)xx < (unsigned)Wd;
        int oc = ((val ? yy : 0) * Wd + (val ? xx : 0)) * (C3 * 2);
        msk[0] = val ? (short)-1 : (short)0;
        rawo[0][0] = *(const s8v*)(pkb + oc + (0 * 4 + lg) * 16);
        rawo[0][1] = *(const s8v*)(pkb + oc + (1 * 4 + lg) * 16);
    }

#pragma unroll
    for (int tt = 0; tt < 3; ++tt) {
        int t = tbase + tt;
        if (tt < 2) {
            int tn = t + 1;
            int yy = y - 1 + tn / 3, xx = x - 1 + tn % 3;
            bool val = (unsigned)yy < (unsigned)Hd && (unsigned)xx < (unsigned)Wd;
            int oc = ((val ? yy : 0) * Wd + (val ? xx : 0)) * (C3 * 2);
            msk[(tt + 1) & 1] = val ? (short)-1 : (short)0;
            rawo[(tt + 1) & 1][0] = *(const s8v*)(pkb + oc + (0 * 4 + lg) * 16);
            rawo[(tt + 1) & 1][1] = *(const s8v*)(pkb + oc + (1 * 4 + lg) * 16);
        }
        short m = msk[tt & 1];
#pragma unroll
        for (int kc = 0; kc < 2; ++kc) {
            s8v bfrag = rawo[tt & 1][kc] & m;
            s8v a0 = Ap[((t * 2 + kc) * 2 + 0) * 64 + L];
            s8v a1 = Ap[((t * 2 + kc) * 2 + 1) * 64 + L];
            acc0 = __builtin_amdgcn_mfma_f32_16x16x32_bf16(a0, bfrag, acc0, 0, 0, 0);
            acc1 = __builtin_amdgcn_mfma_f32_16x16x32_bf16(a1, bfrag, acc1, 0, 0, 0);
        }
    }

    // LDS reduction: waves 1,2 deposit partials; wave 0 sums + writes.
    if (wv != 0) {
        float* r = red[wv - 1] + L * 9;
#pragma unroll
        for (int i = 0; i < 4; ++i) r[i] = acc0[i];
#pragma unroll
        for (int i = 0; i < 4; ++i) r[4 + i] = acc1[i];
    }
    __syncthreads();
    if (wv == 0) {
        const float* r0 = red[0] + L * 9;
        const float* r1 = red[1] + L * 9;
        float* op = off + (size_t)(p0 + px) * 18;
#pragma unroll
        for (int r = 0; r < 4; ++r) {
            int v = lg * 4 + r;
            op[v] = acc0[r] + r0[r] + r1[r] + ob[v];
        }
        if (lg == 0) {
#pragma unroll
            for (int r = 0; r < 2; ++r)
                op[16 + r] = acc1[r] + r0[4 + r] + r1[4 + r] + ob[16 + r];
        }
    }
}

// ===========================================================================
// deform_mfma: M=o(64), N=16 px, K=1728 split over 3 waves (3 taps each),
// LDS reduction. 192-thr blocks, 2304 blocks -> 6.75 waves/SIMD.
// ===========================================================================
struct Ctx {
    int o00, o01, o10, o11;
    float W00, W01, W10, W11;
};

__device__ __forceinline__ Ctx mkctx(int t, int y, int x, float2 o2) {
    Ctx c;
    float py = (float)(y - 1 + t / 3) + o2.x;
    float pxs = (float)(x - 1 + t % 3) + o2.y;
    float fy = floorf(py), fx = floorf(pxs);
    int y0 = (int)fy, x0 = (int)fx;
    int y1 = y0 + 1, x1 = x0 + 1;
    float ay = py - fy, ax = pxs - fx;
    bool vy0 = (unsigned)y0 < (unsigned)Hd;
    bool vy1 = (unsigned)y1 < (unsigned)Hd;
    bool vx0 = (unsigned)x0 < (unsigned)Wd;
    bool vx1 = (unsigned)x1 < (unsigned)Wd;
    c.W00 = (vy0 && vx0) ? (1.f - ay) * (1.f - ax) : 0.f;
    c.W01 = (vy0 && vx1) ? (1.f - ay) * ax : 0.f;
    c.W10 = (vy1 && vx0) ? ay * (1.f - ax) : 0.f;
    c.W11 = (vy1 && vx1) ? ay * ax : 0.f;
    int y0c = min(max(y0, 0), Hd - 1), y1c = min(max(y1, 0), Hd - 1);
    int x0c = min(max(x0, 0), Wd - 1), x1c = min(max(x1, 0), Wd - 1);
    c.o00 = (y0c * Wd + x0c) * (C3 * 2);
    c.o01 = (y0c * Wd + x1c) * (C3 * 2);
    c.o10 = (y1c * Wd + x0c) * (C3 * 2);
    c.o11 = (y1c * Wd + x1c) * (C3 * 2);
    return c;
}

__global__ __launch_bounds__(192) void deform_mfma(
        const bf16* __restrict__ packed,
        const float* __restrict__ off,     // [NPIX][18]
        const bf16* __restrict__ wtb,
        const float* __restrict__ db,
        float* __restrict__ out) {
    __shared__ float red[2][64 * 17];         // 8704 B

    int tid = threadIdx.x;
    int L = tid & 63;
    int wv = tid / 64;                        // 0..2
    int px = L & 15;
    int lg = L >> 4;
    int blk = blockIdx.x;
    int region = (blk & 7) * 288 + (blk >> 3);        // 2304 blocks, XCD swizzle
    int p0 = region * 16;
    int b = p0 / HW;
    int pb = p0 - b * HW;
    int pid = pb + px;
    int x = pid % Wd, y = pid / Wd;
    int tbase = wv * 3;

    const s8v* Ap = (const s8v*)wtb;
    const char* pkb = (const char*)packed + (size_t)b * HW * (C3 * 2);
    const float* offp = off + (size_t)(p0 + px) * 18;

    float2 o2a[3];
#pragma unroll
    for (int tt = 0; tt < 3; ++tt)
        o2a[tt] = *(const float2*)(offp + 2 * (tbase + tt));

    f4v acc[4];
    acc[0] = acc[1] = acc[2] = acc[3] = (f4v){0.f, 0.f, 0.f, 0.f};

    Ctx ctx[2];
    s8v raw[2][12];         // [buf][neighbor*3 + i]

    // prologue: first tap, half 0 (kc 0..2)
    ctx[0] = mkctx(tbase, y, x, o2a[0]);
#pragma unroll
    for (int i = 0; i < 3; ++i) {
        raw[0][0 * 3 + i] = *(const s8v*)(pkb + ctx[0].o00 + (i * 4 + lg) * 16);
        raw[0][1 * 3 + i] = *(const s8v*)(pkb + ctx[0].o01 + (i * 4 + lg) * 16);
        raw[0][2 * 3 + i] = *(const s8v*)(pkb + ctx[0].o10 + (i * 4 + lg) * 16);
        raw[0][3 * 3 + i] = *(const s8v*)(pkb + ctx[0].o11 + (i * 4 + lg) * 16);
    }

#pragma unroll
    for (int h = 0; h < 6; ++h) {             // 3 taps x 2 halves
        int tt = h >> 1;
        int t = tbase + tt;
        int kb = (h & 1) * 3;
        int cbuf = h & 1;
        if (h < 5) {
            int hn = h + 1;
            int ttn = hn >> 1;
            int kbn = (hn & 1) * 3;
            if ((hn & 1) == 0)
                ctx[ttn & 1] = mkctx(tbase + ttn, y, x, o2a[ttn]);
            const Ctx cn = ctx[ttn & 1];
#pragma unroll
            for (int i = 0; i < 3; ++i) {
                int kc = kbn + i;
                raw[hn & 1][0 * 3 + i] = *(const s8v*)(pkb + cn.o00 + (kc * 4 + lg) * 16);
                raw[hn & 1][1 * 3 + i] = *(const s8v*)(pkb + cn.o01 + (kc * 4 + lg) * 16);
                raw[hn & 1][2 * 3 + i] = *(const s8v*)(pkb + cn.o10 + (kc * 4 + lg) * 16);
                raw[hn & 1][3 * 3 + i] = *(const s8v*)(pkb + cn.o11 + (kc * 4 + lg) * 16);
            }
        }
        const Ctx cc = ctx[tt & 1];
#pragma unroll
        for (int i = 0; i < 3; ++i) {
            int kc = kb + i;
            u4v u00 = __builtin_bit_cast(u4v, raw[cbuf][0 * 3 + i]);
            u4v u01 = __builtin_bit_cast(u4v, raw[cbuf][1 * 3 + i]);
            u4v u10 = __builtin_bit_cast(u4v, raw[cbuf][2 * 3 + i]);
            u4v u11 = __builtin_bit_cast(u4v, raw[cbuf][3 * 3 + i]);
            u4v bu;
#pragma unroll
            for (int p = 0; p < 4; ++p) {
                float vlo = cc.W00 * blo(u00[p]) + cc.W01 * blo(u01[p])
                          + cc.W10 * blo(u10[p]) + cc.W11 * blo(u11[p]);
                float vhi = cc.W00 * bhi(u00[p]) + cc.W01 * bhi(u01[p])
                          + cc.W10 * bhi(u10[p]) + cc.W11 * bhi(u11[p]);
                bu[p] = packbf(vlo, vhi);
            }
            s8v bfrag = __builtin_bit_cast(s8v, bu);
#pragma unroll
            for (int mt = 0; mt < 4; ++mt) {
                s8v a = Ap[((t * 6 + kc) * 4 + mt) * 64 + L];
                acc[mt] = __builtin_amdgcn_mfma_f32_16x16x32_bf16(a, bfrag, acc[mt], 0, 0, 0);
            }
        }
    }

    // LDS reduction: waves 1,2 deposit 16 partials/lane; wave 0 sums+stores.
    if (wv != 0) {
        float* r = red[wv - 1] + L * 17;
#pragma unroll
        for (int mt = 0; mt < 4; ++mt)
#pragma unroll
            for (int q = 0; q < 4; ++q)
                r[mt * 4 + q] = acc[mt][q];
    }
    __syncthreads();
    if (wv == 0) {
        const float* r0 = red[0] + L * 17;
        const float* r1 = red[1] + L * 17;
#pragma unroll
        for (int mt = 0; mt < 4; ++mt) {
#pragma unroll
            for (int q = 0; q < 4; ++q) {
                int o = mt * 16 + lg * 4 + q;
                float v = acc[mt][q] + r0[mt * 4 + q] + r1[mt * 4 + q] + db[o];
                out[((size_t)(b * On + o)) * HW + pb + px] = fmaxf(v, 0.f);
            }
        }
    }
}

// ---------------------------------------------------------------------------
extern "C" void kernel_launch(void* const* d_in, const int* in_sizes, int n_in,
                              void* d_out, int out_size, void* d_ws, size_t ws_size,
                              hipStream_t stream) {
    const float* ref  = (const float*)d_in[0];
    const float* dist = (const float*)d_in[1];
    const float* ow   = (const float*)d_in[2];
    const float* ob   = (const float*)d_in[3];
    const float* dw   = (const float*)d_in[4];
    const float* db   = (const float*)d_in[5];

    float* out = (float*)d_out;               // [feat | diff], each NFEAT f32

    // ws: off [NPIX][18] f32 | wtb bf16 | wtb2 bf16 | packed bf16 [NPIX][192]
    float* ws_off = (float*)d_ws;
    bf16* ws_wtb  = (bf16*)((char*)d_ws + (size_t)NPIX * 18 * 4);
    bf16* ws_wtb2 = ws_wtb + NWTB;
    bf16* ws_pk   = ws_wtb2 + NWTB2;

    repack_kernel<<<Bn * (HW / 64), 256, 0, stream>>>(
        ref, dist, (unsigned int*)ws_pk, out + NFEAT);
    wts_kernel<<<(NWTB + NWTB2 + 255) / 256, 256, 0, stream>>>(
        dw, ow, ws_wtb, ws_wtb2);
    offset_mfma<<<NPIX / 16, 192, 0, stream>>>(ws_pk, ws_wtb2, ob, ws_off);
    deform_mfma<<<NPIX / 16, 192, 0, stream>>>(ws_pk, ws_off, ws_wtb, db, out);
}